// Round 1
// baseline (1004.582 us; speedup 1.0000x reference)
//
#include <hip/hip_runtime.h>
#include <cstdint>
#include <cstddef>

#define F_IN  128
#define F_HID 64
#define F_OUT 40

// ---------------------------------------------------------------------------
// GEMM1: xw[N,64] = x[N,128] @ W1[128,64]
// One wave per row, lane = output col. x row loads are wave-uniform float4
// (L1 broadcast); W1 loads coalesce 256B/lane-instr and W1 (32KB) stays L1-hot.
// ---------------------------------------------------------------------------
__global__ __launch_bounds__(256) void gemm1_k(const float* __restrict__ x,
                                               const float* __restrict__ W1,
                                               float* __restrict__ xw, int N) {
  int row = (blockIdx.x * 256 + threadIdx.x) >> 6;
  int col = threadIdx.x & 63;
  if (row >= N) return;
  const float* xr = x + (size_t)row * F_IN;
  float acc = 0.f;
#pragma unroll
  for (int k = 0; k < F_IN; k += 4) {
    float4 xv = *(const float4*)(xr + k);
    acc = fmaf(xv.x, W1[(k + 0) * F_HID + col], acc);
    acc = fmaf(xv.y, W1[(k + 1) * F_HID + col], acc);
    acc = fmaf(xv.z, W1[(k + 2) * F_HID + col], acc);
    acc = fmaf(xv.w, W1[(k + 3) * F_HID + col], acc);
  }
  xw[(size_t)row * F_HID + col] = acc;
}

// ---------------------------------------------------------------------------
// Scatter-sum (hidden layer): agg[dst[e]][j] += xw[src[e]][j], j in [0,64)
// One wave per edge (e = tid>>6 is wave-uniform -> scalar src/dst loads),
// gather + atomic are both 256B contiguous per wave.
// ---------------------------------------------------------------------------
__global__ __launch_bounds__(256) void scatter_hid_k(const float* __restrict__ xw,
                                                     const int* __restrict__ ei,
                                                     float* __restrict__ agg, int E) {
  int t = blockIdx.x * 256 + threadIdx.x;
  int e = t >> 6;
  if (e >= E) return;
  int j = t & 63;
  int s = ei[e];
  int d = ei[E + e];
  float v = xw[(size_t)s * F_HID + j];
  unsafeAtomicAdd(&agg[(size_t)d * F_HID + j], v);
}

// ---------------------------------------------------------------------------
// GEMM2 (+bias1, +ReLU fused on the read): hw[N,40] = relu(agg1+b1) @ W2[64,40]
// Wave per row; lanes >= 40 compute a clamped column (no divergence) and skip
// the store.
// ---------------------------------------------------------------------------
__global__ __launch_bounds__(256) void gemm2_k(const float* __restrict__ agg1,
                                               const float* __restrict__ b1,
                                               const float* __restrict__ W2,
                                               float* __restrict__ hw, int N) {
  int row = (blockIdx.x * 256 + threadIdx.x) >> 6;
  int lane = threadIdx.x & 63;
  if (row >= N) return;
  int col = lane < F_OUT ? lane : F_OUT - 1;
  const float* hr = agg1 + (size_t)row * F_HID;
  float acc = 0.f;
#pragma unroll
  for (int k = 0; k < F_HID; k += 4) {
    float4 hv = *(const float4*)(hr + k);
    float h0 = fmaxf(hv.x + b1[k + 0], 0.f);
    float h1 = fmaxf(hv.y + b1[k + 1], 0.f);
    float h2 = fmaxf(hv.z + b1[k + 2], 0.f);
    float h3 = fmaxf(hv.w + b1[k + 3], 0.f);
    acc = fmaf(h0, W2[(k + 0) * F_OUT + col], acc);
    acc = fmaf(h1, W2[(k + 1) * F_OUT + col], acc);
    acc = fmaf(h2, W2[(k + 2) * F_OUT + col], acc);
    acc = fmaf(h3, W2[(k + 3) * F_OUT + col], acc);
  }
  if (lane < F_OUT) hw[(size_t)row * F_OUT + lane] = acc;
}

// ---------------------------------------------------------------------------
// Scatter-sum (output layer) directly into d_out (pre-zeroed):
// out[dst[e]][j] += hw[src[e]][j], j in [0,40)
// ---------------------------------------------------------------------------
__global__ __launch_bounds__(256) void scatter_out_k(const float* __restrict__ hw,
                                                     const int* __restrict__ ei,
                                                     float* __restrict__ agg2, int E) {
  int t = blockIdx.x * 256 + threadIdx.x;
  int e = t / F_OUT;
  if (e >= E) return;
  int j = t - e * F_OUT;
  int s = ei[e];
  int d = ei[E + e];
  unsafeAtomicAdd(&agg2[(size_t)d * F_OUT + j], hw[(size_t)s * F_OUT + j]);
}

// ---------------------------------------------------------------------------
// In-place +bias2 and log_softmax over 40 classes. One wave per row; lanes
// >= 40 hold neutral elements for the shuffle reductions.
// ---------------------------------------------------------------------------
__global__ __launch_bounds__(256) void logsoftmax_k(float* __restrict__ out,
                                                    const float* __restrict__ b2, int N) {
  int row = (blockIdx.x * 256 + threadIdx.x) >> 6;
  int lane = threadIdx.x & 63;
  if (row >= N) return;
  float* r = out + (size_t)row * F_OUT;
  float val = 0.f;
  float m = -3.4e38f;
  if (lane < F_OUT) {
    val = r[lane] + b2[lane];
    m = val;
  }
#pragma unroll
  for (int off = 32; off; off >>= 1) m = fmaxf(m, __shfl_xor(m, off, 64));
  float ex = (lane < F_OUT) ? __expf(val - m) : 0.f;
#pragma unroll
  for (int off = 32; off; off >>= 1) ex += __shfl_xor(ex, off, 64);
  float lse = __logf(ex) + m;
  if (lane < F_OUT) r[lane] = val - lse;
}

// ---------------------------------------------------------------------------
// Launch. ws layout: [ buf0: N*64 floats (xw, later reused for hw) |
//                      agg1: N*64 floats ]  => 51.2 MB total.
// agg2 lives directly in d_out (zeroed each call; harness poisons it).
// ---------------------------------------------------------------------------
extern "C" void kernel_launch(void* const* d_in, const int* in_sizes, int n_in,
                              void* d_out, int out_size, void* d_ws, size_t ws_size,
                              hipStream_t stream) {
  const float* x  = (const float*)d_in[0];
  const int*   ei = (const int*)d_in[1];
  const float* W1 = (const float*)d_in[2];
  const float* b1 = (const float*)d_in[3];
  const float* W2 = (const float*)d_in[4];
  const float* b2 = (const float*)d_in[5];

  int N = in_sizes[0] / F_IN;
  int E = in_sizes[1] / 2;

  float* buf0 = (float*)d_ws;                       // xw, then hw
  float* agg1 = buf0 + (size_t)N * F_HID;
  float* out  = (float*)d_out;

  hipMemsetAsync(agg1, 0, (size_t)N * F_HID * sizeof(float), stream);
  hipMemsetAsync(out, 0, (size_t)N * F_OUT * sizeof(float), stream);

  int rowsGrid = (N * 64 + 255) / 256;
  gemm1_k<<<rowsGrid, 256, 0, stream>>>(x, W1, buf0, N);

  int sc1Grid = (int)(((int64_t)E * 64 + 255) / 256);
  scatter_hid_k<<<sc1Grid, 256, 0, stream>>>(buf0, ei, agg1, E);

  gemm2_k<<<rowsGrid, 256, 0, stream>>>(agg1, b1, W2, buf0, N);

  int sc2Grid = (int)(((int64_t)E * F_OUT + 255) / 256);
  scatter_out_k<<<sc2Grid, 256, 0, stream>>>(buf0, ei, out, E);

  logsoftmax_k<<<rowsGrid, 256, 0, stream>>>(out, b2, N);
}

// Round 2
// 700.388 us; speedup vs baseline: 1.4343x; 1.4343x over previous
//
#include <hip/hip_runtime.h>
#include <cstdint>
#include <cstddef>

#define F_IN  128
#define F_HID 64
#define F_OUT 40

// ---------------------------------------------------------------------------
// GEMM1: xw[N,64] = x[N,128] @ W1[128,64]. Wave per row, lane = col.
// ---------------------------------------------------------------------------
__global__ __launch_bounds__(256) void gemm1_k(const float* __restrict__ x,
                                               const float* __restrict__ W1,
                                               float* __restrict__ xw, int N) {
  int row = (blockIdx.x * 256 + threadIdx.x) >> 6;
  int col = threadIdx.x & 63;
  if (row >= N) return;
  const float* xr = x + (size_t)row * F_IN;
  float acc = 0.f;
#pragma unroll
  for (int k = 0; k < F_IN; k += 4) {
    float4 xv = *(const float4*)(xr + k);
    acc = fmaf(xv.x, W1[(k + 0) * F_HID + col], acc);
    acc = fmaf(xv.y, W1[(k + 1) * F_HID + col], acc);
    acc = fmaf(xv.z, W1[(k + 2) * F_HID + col], acc);
    acc = fmaf(xv.w, W1[(k + 3) * F_HID + col], acc);
  }
  xw[(size_t)row * F_HID + col] = acc;
}

// ---------------------------------------------------------------------------
// CSR build: degree histogram -> hierarchical exclusive scan -> cursor fill.
// ---------------------------------------------------------------------------
__global__ __launch_bounds__(256) void hist_k(const int* __restrict__ ei,
                                              int* __restrict__ deg, int E) {
  int e = blockIdx.x * 256 + threadIdx.x;
  if (e < E) atomicAdd(&deg[ei[E + e]], 1);
}

__global__ __launch_bounds__(256) void blocksum_k(const int* __restrict__ deg,
                                                  int* __restrict__ bsum, int N) {
  int i = blockIdx.x * 256 + threadIdx.x;
  int v = (i < N) ? deg[i] : 0;
#pragma unroll
  for (int off = 32; off; off >>= 1) v += __shfl_xor(v, off, 64);
  __shared__ int sm[4];
  if ((threadIdx.x & 63) == 0) sm[threadIdx.x >> 6] = v;
  __syncthreads();
  if (threadIdx.x == 0) bsum[blockIdx.x] = sm[0] + sm[1] + sm[2] + sm[3];
}

// Single-block exclusive scan of per-chunk sums (nChunks <= 512).
__global__ __launch_bounds__(512) void scanbsum_k(int* __restrict__ bsum, int nChunks,
                                                  int* __restrict__ row_ptr, int N, int E) {
  __shared__ int sm[512];
  int t = threadIdx.x;
  int v = (t < nChunks) ? bsum[t] : 0;
  sm[t] = v;
  __syncthreads();
  for (int off = 1; off < 512; off <<= 1) {
    int add = (t >= off) ? sm[t - off] : 0;
    __syncthreads();
    sm[t] += add;
    __syncthreads();
  }
  if (t < nChunks) bsum[t] = (t == 0) ? 0 : sm[t - 1];
  if (t == 0) row_ptr[N] = E;
}

__global__ __launch_bounds__(256) void rowptr_k(const int* __restrict__ deg,
                                                const int* __restrict__ boff,
                                                int* __restrict__ row_ptr,
                                                int* __restrict__ cursor, int N) {
  __shared__ int sm[256];
  int t = threadIdx.x;
  int i = blockIdx.x * 256 + t;
  int v = (i < N) ? deg[i] : 0;
  sm[t] = v;
  __syncthreads();
  for (int off = 1; off < 256; off <<= 1) {
    int add = (t >= off) ? sm[t - off] : 0;
    __syncthreads();
    sm[t] += add;
    __syncthreads();
  }
  if (i < N) {
    int excl = sm[t] - v + boff[blockIdx.x];   // exclusive prefix
    row_ptr[i] = excl;
    cursor[i] = excl;
  }
}

__global__ __launch_bounds__(256) void fill_k(const int* __restrict__ ei,
                                              int* __restrict__ cursor,
                                              int* __restrict__ csr, int E) {
  int e = blockIdx.x * 256 + threadIdx.x;
  if (e >= E) return;
  int d = ei[E + e];
  int pos = atomicAdd(&cursor[d], 1);
  csr[pos] = ei[e];
}

// ---------------------------------------------------------------------------
// Aggregation layer 1: agg1[n][j] = sum_{s in nbrs(n)} xw[s][j]. Wave per
// node; lanes cooperatively load 64 src ids then broadcast via shuffle —
// no per-iteration uniform loads, gathers are 256B contiguous per wave.
// ---------------------------------------------------------------------------
__global__ __launch_bounds__(256) void agg1_k(const float* __restrict__ xw,
                                              const int* __restrict__ row_ptr,
                                              const int* __restrict__ csr,
                                              float* __restrict__ agg, int N) {
  int row = (blockIdx.x * 256 + threadIdx.x) >> 6;
  int lane = threadIdx.x & 63;
  if (row >= N) return;
  int start = row_ptr[row], end = row_ptr[row + 1];
  float a0 = 0.f, a1 = 0.f;
  for (int base = start; base < end; base += 64) {
    int myS = (base + lane < end) ? csr[base + lane] : 0;
    int cnt = min(64, end - base);
    int k = 0;
    for (; k + 1 < cnt; k += 2) {
      int s0 = __shfl(myS, k, 64);
      int s1 = __shfl(myS, k + 1, 64);
      a0 += xw[(size_t)s0 * F_HID + lane];
      a1 += xw[(size_t)s1 * F_HID + lane];
    }
    if (k < cnt) a0 += xw[(size_t)__shfl(myS, k, 64) * F_HID + lane];
  }
  agg[(size_t)row * F_HID + lane] = a0 + a1;
}

// ---------------------------------------------------------------------------
// GEMM2 (+bias1 +ReLU fused on read): hw[N,40] = relu(agg1+b1) @ W2[64,40]
// ---------------------------------------------------------------------------
__global__ __launch_bounds__(256) void gemm2_k(const float* __restrict__ agg1,
                                               const float* __restrict__ b1,
                                               const float* __restrict__ W2,
                                               float* __restrict__ hw, int N) {
  int row = (blockIdx.x * 256 + threadIdx.x) >> 6;
  int lane = threadIdx.x & 63;
  if (row >= N) return;
  int col = lane < F_OUT ? lane : F_OUT - 1;
  const float* hr = agg1 + (size_t)row * F_HID;
  float acc = 0.f;
#pragma unroll
  for (int k = 0; k < F_HID; k += 4) {
    float4 hv = *(const float4*)(hr + k);
    float h0 = fmaxf(hv.x + b1[k + 0], 0.f);
    float h1 = fmaxf(hv.y + b1[k + 1], 0.f);
    float h2 = fmaxf(hv.z + b1[k + 2], 0.f);
    float h3 = fmaxf(hv.w + b1[k + 3], 0.f);
    acc = fmaf(h0, W2[(k + 0) * F_OUT + col], acc);
    acc = fmaf(h1, W2[(k + 1) * F_OUT + col], acc);
    acc = fmaf(h2, W2[(k + 2) * F_OUT + col], acc);
    acc = fmaf(h3, W2[(k + 3) * F_OUT + col], acc);
  }
  if (lane < F_OUT) hw[(size_t)row * F_OUT + lane] = acc;
}

// ---------------------------------------------------------------------------
// Aggregation layer 2 fused with +bias2 and log_softmax. Wave per node.
// ---------------------------------------------------------------------------
__global__ __launch_bounds__(256) void agg2_ls_k(const float* __restrict__ hw,
                                                 const int* __restrict__ row_ptr,
                                                 const int* __restrict__ csr,
                                                 const float* __restrict__ b2,
                                                 float* __restrict__ out, int N) {
  int row = (blockIdx.x * 256 + threadIdx.x) >> 6;
  int lane = threadIdx.x & 63;
  if (row >= N) return;
  int col = lane < F_OUT ? lane : F_OUT - 1;
  int start = row_ptr[row], end = row_ptr[row + 1];
  float a0 = 0.f, a1 = 0.f;
  for (int base = start; base < end; base += 64) {
    int myS = (base + lane < end) ? csr[base + lane] : 0;
    int cnt = min(64, end - base);
    int k = 0;
    for (; k + 1 < cnt; k += 2) {
      int s0 = __shfl(myS, k, 64);
      int s1 = __shfl(myS, k + 1, 64);
      a0 += hw[(size_t)s0 * F_OUT + col];
      a1 += hw[(size_t)s1 * F_OUT + col];
    }
    if (k < cnt) a0 += hw[(size_t)__shfl(myS, k, 64) * F_OUT + col];
  }
  float val = 0.f, m = -3.4e38f;
  if (lane < F_OUT) { val = a0 + a1 + b2[lane]; m = val; }
#pragma unroll
  for (int off = 32; off; off >>= 1) m = fmaxf(m, __shfl_xor(m, off, 64));
  float ex = (lane < F_OUT) ? __expf(val - m) : 0.f;
#pragma unroll
  for (int off = 32; off; off >>= 1) ex += __shfl_xor(ex, off, 64);
  float lse = __logf(ex) + m;
  if (lane < F_OUT) out[(size_t)row * F_OUT + lane] = val - lse;
}

// ---------------------------------------------------------------------------
// ws layout (≈58.8 MB):
//   xw   : N*64 f32 (reused as hw[N,40] after agg1 consumes it)
//   agg1 : N*64 f32
//   deg  : N int | row_ptr : N+1 int | cursor : N int | bsum : 1024 int
//   csr  : E int
// ---------------------------------------------------------------------------
extern "C" void kernel_launch(void* const* d_in, const int* in_sizes, int n_in,
                              void* d_out, int out_size, void* d_ws, size_t ws_size,
                              hipStream_t stream) {
  const float* x  = (const float*)d_in[0];
  const int*   ei = (const int*)d_in[1];
  const float* W1 = (const float*)d_in[2];
  const float* b1 = (const float*)d_in[3];
  const float* W2 = (const float*)d_in[4];
  const float* b2 = (const float*)d_in[5];

  int N = in_sizes[0] / F_IN;
  int E = in_sizes[1] / 2;

  float* xw   = (float*)d_ws;
  float* agg1 = xw + (size_t)N * F_HID;
  int* deg     = (int*)(agg1 + (size_t)N * F_HID);
  int* row_ptr = deg + N;
  int* cursor  = row_ptr + N + 1;
  int* bsum    = cursor + N;
  int* csr     = bsum + 1024;
  float* hw = xw;   // reuse after agg1_k
  float* out = (float*)d_out;

  int nChunks = (N + 255) / 256;
  int edgeGrid = (E + 255) / 256;
  int rowsGrid = (N * 64 + 255) / 256;

  hipMemsetAsync(deg, 0, (size_t)N * sizeof(int), stream);

  gemm1_k<<<rowsGrid, 256, 0, stream>>>(x, W1, xw, N);

  hist_k<<<edgeGrid, 256, 0, stream>>>(ei, deg, E);
  blocksum_k<<<nChunks, 256, 0, stream>>>(deg, bsum, N);
  scanbsum_k<<<1, 512, 0, stream>>>(bsum, nChunks, row_ptr, N, E);
  rowptr_k<<<nChunks, 256, 0, stream>>>(deg, bsum, row_ptr, cursor, N);
  fill_k<<<edgeGrid, 256, 0, stream>>>(ei, cursor, csr, E);

  agg1_k<<<rowsGrid, 256, 0, stream>>>(xw, row_ptr, csr, agg1, N);
  gemm2_k<<<rowsGrid, 256, 0, stream>>>(agg1, b1, W2, hw, N);
  agg2_ls_k<<<rowsGrid, 256, 0, stream>>>(hw, row_ptr, csr, b2, out, N);
}

// Round 3
// 514.994 us; speedup vs baseline: 1.9507x; 1.3600x over previous
//
#include <hip/hip_runtime.h>
#include <cstdint>
#include <cstddef>

#define F_IN  128
#define F_HID 64
#define F_OUT 40
#define RB    8    // rows per wave in the register-blocked GEMMs

// ---------------------------------------------------------------------------
// GEMM1: xw[N,64] = x[N,128] @ W1[128,64].
// Wave computes RB=8 rows x 64 cols. lane = col. W1 loads amortized 8x
// (128 VMEM dword/wave); x rows are wave-uniform -> scalar s_load path.
// ---------------------------------------------------------------------------
__global__ __launch_bounds__(256) void gemm1_k(const float* __restrict__ x,
                                               const float* __restrict__ W1,
                                               float* __restrict__ xw, int N) {
  int wave = (blockIdx.x * 256 + threadIdx.x) >> 6;
  int lane = threadIdx.x & 63;
  int row0 = wave * RB;
  if (row0 >= N) return;

  if (row0 + RB <= N) {
    row0 = __builtin_amdgcn_readfirstlane(row0);
    const float* xr = x + (size_t)row0 * F_IN;
    float acc[RB];
#pragma unroll
    for (int r = 0; r < RB; ++r) acc[r] = 0.f;

    for (int k0 = 0; k0 < F_IN; k0 += 8) {
      float w[8];
#pragma unroll
      for (int kk = 0; kk < 8; ++kk) w[kk] = W1[(k0 + kk) * F_HID + lane];
#pragma unroll
      for (int r = 0; r < RB; ++r) {
        const float* xp = xr + r * F_IN + k0;   // uniform address -> s_load
#pragma unroll
        for (int kk = 0; kk < 8; ++kk)
          acc[r] = fmaf(xp[kk], w[kk], acc[r]);
      }
    }
#pragma unroll
    for (int r = 0; r < RB; ++r)
      xw[(size_t)(row0 + r) * F_HID + lane] = acc[r];
  } else {
    // tail: per-row fallback
    for (int r = 0; r < RB && row0 + r < N; ++r) {
      const float* xr = x + (size_t)(row0 + r) * F_IN;
      float acc = 0.f;
      for (int k = 0; k < F_IN; ++k) acc = fmaf(xr[k], W1[k * F_HID + lane], acc);
      xw[(size_t)(row0 + r) * F_HID + lane] = acc;
    }
  }
}

// ---------------------------------------------------------------------------
// CSR build: degree histogram -> hierarchical exclusive scan -> cursor fill.
// ---------------------------------------------------------------------------
__global__ __launch_bounds__(256) void hist_k(const int* __restrict__ ei,
                                              int* __restrict__ deg, int E) {
  int e = blockIdx.x * 256 + threadIdx.x;
  if (e < E) atomicAdd(&deg[ei[E + e]], 1);
}

__global__ __launch_bounds__(256) void blocksum_k(const int* __restrict__ deg,
                                                  int* __restrict__ bsum, int N) {
  int i = blockIdx.x * 256 + threadIdx.x;
  int v = (i < N) ? deg[i] : 0;
#pragma unroll
  for (int off = 32; off; off >>= 1) v += __shfl_xor(v, off, 64);
  __shared__ int sm[4];
  if ((threadIdx.x & 63) == 0) sm[threadIdx.x >> 6] = v;
  __syncthreads();
  if (threadIdx.x == 0) bsum[blockIdx.x] = sm[0] + sm[1] + sm[2] + sm[3];
}

__global__ __launch_bounds__(512) void scanbsum_k(int* __restrict__ bsum, int nChunks,
                                                  int* __restrict__ row_ptr, int N, int E) {
  __shared__ int sm[512];
  int t = threadIdx.x;
  int v = (t < nChunks) ? bsum[t] : 0;
  sm[t] = v;
  __syncthreads();
  for (int off = 1; off < 512; off <<= 1) {
    int add = (t >= off) ? sm[t - off] : 0;
    __syncthreads();
    sm[t] += add;
    __syncthreads();
  }
  if (t < nChunks) bsum[t] = (t == 0) ? 0 : sm[t - 1];
  if (t == 0) row_ptr[N] = E;
}

__global__ __launch_bounds__(256) void rowptr_k(const int* __restrict__ deg,
                                                const int* __restrict__ boff,
                                                int* __restrict__ row_ptr,
                                                int* __restrict__ cursor, int N) {
  __shared__ int sm[256];
  int t = threadIdx.x;
  int i = blockIdx.x * 256 + t;
  int v = (i < N) ? deg[i] : 0;
  sm[t] = v;
  __syncthreads();
  for (int off = 1; off < 256; off <<= 1) {
    int add = (t >= off) ? sm[t - off] : 0;
    __syncthreads();
    sm[t] += add;
    __syncthreads();
  }
  if (i < N) {
    int excl = sm[t] - v + boff[blockIdx.x];
    row_ptr[i] = excl;
    cursor[i] = excl;
  }
}

__global__ __launch_bounds__(256) void fill_k(const int* __restrict__ ei,
                                              int* __restrict__ cursor,
                                              int* __restrict__ csr, int E) {
  int e = blockIdx.x * 256 + threadIdx.x;
  if (e >= E) return;
  int d = ei[E + e];
  int pos = atomicAdd(&cursor[d], 1);
  csr[pos] = ei[e];
}

// ---------------------------------------------------------------------------
// Aggregation layer 1 + fused bias1 + ReLU:
//   agg1[n][j] = relu( sum_{s in nbrs(n)} xw[s][j] + b1[j] )
// Wave per node; src ids loaded cooperatively then shuffle-broadcast.
// ---------------------------------------------------------------------------
__global__ __launch_bounds__(256) void agg1_k(const float* __restrict__ xw,
                                              const int* __restrict__ row_ptr,
                                              const int* __restrict__ csr,
                                              const float* __restrict__ b1,
                                              float* __restrict__ agg, int N) {
  int row = (blockIdx.x * 256 + threadIdx.x) >> 6;
  int lane = threadIdx.x & 63;
  if (row >= N) return;
  int start = row_ptr[row], end = row_ptr[row + 1];
  float a0 = 0.f, a1 = 0.f;
  for (int base = start; base < end; base += 64) {
    int myS = (base + lane < end) ? csr[base + lane] : 0;
    int cnt = min(64, end - base);
    int k = 0;
    for (; k + 1 < cnt; k += 2) {
      int s0 = __shfl(myS, k, 64);
      int s1 = __shfl(myS, k + 1, 64);
      a0 += xw[(size_t)s0 * F_HID + lane];
      a1 += xw[(size_t)s1 * F_HID + lane];
    }
    if (k < cnt) a0 += xw[(size_t)__shfl(myS, k, 64) * F_HID + lane];
  }
  agg[(size_t)row * F_HID + lane] = fmaxf(a0 + a1 + b1[lane], 0.f);
}

// ---------------------------------------------------------------------------
// GEMM2: hw[N,40] = h[N,64] @ W2[64,40]   (h already bias'd+ReLU'd)
// Register-blocked like gemm1: RB rows/wave, W2 amortized, h scalar loads.
// ---------------------------------------------------------------------------
__global__ __launch_bounds__(256) void gemm2_k(const float* __restrict__ h,
                                               const float* __restrict__ W2,
                                               float* __restrict__ hw, int N) {
  int wave = (blockIdx.x * 256 + threadIdx.x) >> 6;
  int lane = threadIdx.x & 63;
  int col = lane < F_OUT ? lane : F_OUT - 1;
  int row0 = wave * RB;
  if (row0 >= N) return;

  if (row0 + RB <= N) {
    row0 = __builtin_amdgcn_readfirstlane(row0);
    const float* hr = h + (size_t)row0 * F_HID;
    float acc[RB];
#pragma unroll
    for (int r = 0; r < RB; ++r) acc[r] = 0.f;

    for (int k0 = 0; k0 < F_HID; k0 += 8) {
      float w[8];
#pragma unroll
      for (int kk = 0; kk < 8; ++kk) w[kk] = W2[(k0 + kk) * F_OUT + col];
#pragma unroll
      for (int r = 0; r < RB; ++r) {
        const float* hp = hr + r * F_HID + k0;  // uniform -> s_load
#pragma unroll
        for (int kk = 0; kk < 8; ++kk)
          acc[r] = fmaf(hp[kk], w[kk], acc[r]);
      }
    }
    if (lane < F_OUT) {
#pragma unroll
      for (int r = 0; r < RB; ++r)
        hw[(size_t)(row0 + r) * F_OUT + lane] = acc[r];
    }
  } else {
    for (int r = 0; r < RB && row0 + r < N; ++r) {
      const float* hr = h + (size_t)(row0 + r) * F_HID;
      float acc = 0.f;
      for (int k = 0; k < F_HID; ++k) acc = fmaf(hr[k], W2[k * F_OUT + col], acc);
      if (lane < F_OUT) hw[(size_t)(row0 + r) * F_OUT + lane] = acc;
    }
  }
}

// ---------------------------------------------------------------------------
// Aggregation layer 2 fused with +bias2 and log_softmax. Wave per node.
// ---------------------------------------------------------------------------
__global__ __launch_bounds__(256) void agg2_ls_k(const float* __restrict__ hw,
                                                 const int* __restrict__ row_ptr,
                                                 const int* __restrict__ csr,
                                                 const float* __restrict__ b2,
                                                 float* __restrict__ out, int N) {
  int row = (blockIdx.x * 256 + threadIdx.x) >> 6;
  int lane = threadIdx.x & 63;
  if (row >= N) return;
  int col = lane < F_OUT ? lane : F_OUT - 1;
  int start = row_ptr[row], end = row_ptr[row + 1];
  float a0 = 0.f, a1 = 0.f;
  for (int base = start; base < end; base += 64) {
    int myS = (base + lane < end) ? csr[base + lane] : 0;
    int cnt = min(64, end - base);
    int k = 0;
    for (; k + 1 < cnt; k += 2) {
      int s0 = __shfl(myS, k, 64);
      int s1 = __shfl(myS, k + 1, 64);
      a0 += hw[(size_t)s0 * F_OUT + col];
      a1 += hw[(size_t)s1 * F_OUT + col];
    }
    if (k < cnt) a0 += hw[(size_t)__shfl(myS, k, 64) * F_OUT + col];
  }
  float val = 0.f, m = -3.4e38f;
  if (lane < F_OUT) { val = a0 + a1 + b2[lane]; m = val; }
#pragma unroll
  for (int off = 32; off; off >>= 1) m = fmaxf(m, __shfl_xor(m, off, 64));
  float ex = (lane < F_OUT) ? __expf(val - m) : 0.f;
#pragma unroll
  for (int off = 32; off; off >>= 1) ex += __shfl_xor(ex, off, 64);
  float lse = __logf(ex) + m;
  if (lane < F_OUT) out[(size_t)row * F_OUT + lane] = val - lse;
}

// ---------------------------------------------------------------------------
// ws layout (≈58.8 MB):
//   xw   : N*64 f32 (reused as hw[N,40] after agg1 consumes it)
//   agg1 : N*64 f32
//   deg  : N int | row_ptr : N+1 int | cursor : N int | bsum : 1024 int
//   csr  : E int
// ---------------------------------------------------------------------------
extern "C" void kernel_launch(void* const* d_in, const int* in_sizes, int n_in,
                              void* d_out, int out_size, void* d_ws, size_t ws_size,
                              hipStream_t stream) {
  const float* x  = (const float*)d_in[0];
  const int*   ei = (const int*)d_in[1];
  const float* W1 = (const float*)d_in[2];
  const float* b1 = (const float*)d_in[3];
  const float* W2 = (const float*)d_in[4];
  const float* b2 = (const float*)d_in[5];

  int N = in_sizes[0] / F_IN;
  int E = in_sizes[1] / 2;

  float* xw   = (float*)d_ws;
  float* agg1 = xw + (size_t)N * F_HID;
  int* deg     = (int*)(agg1 + (size_t)N * F_HID);
  int* row_ptr = deg + N;
  int* cursor  = row_ptr + N + 1;
  int* bsum    = cursor + N;
  int* csr     = bsum + 1024;
  float* hw = xw;   // reuse after agg1_k
  float* out = (float*)d_out;

  int nChunks = (N + 255) / 256;
  int edgeGrid = (E + 255) / 256;
  int rowsGrid = (N * 64 + 255) / 256;                 // wave-per-row kernels
  int gemmGrid = ((N + RB - 1) / RB * 64 + 255) / 256; // wave-per-RB-rows

  hipMemsetAsync(deg, 0, (size_t)N * sizeof(int), stream);

  gemm1_k<<<gemmGrid, 256, 0, stream>>>(x, W1, xw, N);

  hist_k<<<edgeGrid, 256, 0, stream>>>(ei, deg, E);
  blocksum_k<<<nChunks, 256, 0, stream>>>(deg, bsum, N);
  scanbsum_k<<<1, 512, 0, stream>>>(bsum, nChunks, row_ptr, N, E);
  rowptr_k<<<nChunks, 256, 0, stream>>>(deg, bsum, row_ptr, cursor, N);
  fill_k<<<edgeGrid, 256, 0, stream>>>(ei, cursor, csr, E);

  agg1_k<<<rowsGrid, 256, 0, stream>>>(xw, row_ptr, csr, b1, agg1, N);
  gemm2_k<<<gemmGrid, 256, 0, stream>>>(agg1, W2, hw, N);
  agg2_ls_k<<<rowsGrid, 256, 0, stream>>>(hw, row_ptr, csr, b2, out, N);
}

// Round 4
// 489.817 us; speedup vs baseline: 2.0509x; 1.0514x over previous
//
#include <hip/hip_runtime.h>
#include <cstdint>
#include <cstddef>

#define F_IN  128
#define F_HID 64
#define F_OUT 40
#define RB    8     // rows per wave in the register-blocked GEMMs

#define NBMAX 32    // max dst-buckets (bucket = dst >> 12; N=100k -> 25 used)
#define CHUNK 4096  // edges per partition block

// ---------------------------------------------------------------------------
// GEMM1: xw[N,64] = x[N,128] @ W1[128,64]. Wave computes RB=8 rows x 64 cols.
// W1 loads amortized 8x; x rows wave-uniform -> scalar s_load path.
// ---------------------------------------------------------------------------
__global__ __launch_bounds__(256) void gemm1_k(const float* __restrict__ x,
                                               const float* __restrict__ W1,
                                               float* __restrict__ xw, int N) {
  int wave = (blockIdx.x * 256 + threadIdx.x) >> 6;
  int lane = threadIdx.x & 63;
  int row0 = wave * RB;
  if (row0 >= N) return;

  if (row0 + RB <= N) {
    row0 = __builtin_amdgcn_readfirstlane(row0);
    const float* xr = x + (size_t)row0 * F_IN;
    float acc[RB];
#pragma unroll
    for (int r = 0; r < RB; ++r) acc[r] = 0.f;

    for (int k0 = 0; k0 < F_IN; k0 += 8) {
      float w[8];
#pragma unroll
      for (int kk = 0; kk < 8; ++kk) w[kk] = W1[(k0 + kk) * F_HID + lane];
#pragma unroll
      for (int r = 0; r < RB; ++r) {
        const float* xp = xr + r * F_IN + k0;
#pragma unroll
        for (int kk = 0; kk < 8; ++kk)
          acc[r] = fmaf(xp[kk], w[kk], acc[r]);
      }
    }
#pragma unroll
    for (int r = 0; r < RB; ++r)
      xw[(size_t)(row0 + r) * F_HID + lane] = acc[r];
  } else {
    for (int r = 0; r < RB && row0 + r < N; ++r) {
      const float* xr = x + (size_t)(row0 + r) * F_IN;
      float acc = 0.f;
      for (int k = 0; k < F_IN; ++k) acc = fmaf(xr[k], W1[k * F_HID + lane], acc);
      xw[(size_t)(row0 + r) * F_HID + lane] = acc;
    }
  }
}

// ---------------------------------------------------------------------------
// Per-node degree histogram (deg is 400KB -> L2-resident, atomics cheap).
// ---------------------------------------------------------------------------
__global__ __launch_bounds__(256) void hist_k(const int* __restrict__ ei,
                                              int* __restrict__ deg, int E) {
  int e = blockIdx.x * 256 + threadIdx.x;
  if (e < E) atomicAdd(&deg[ei[E + e]], 1);
}

__global__ __launch_bounds__(256) void blocksum_k(const int* __restrict__ deg,
                                                  int* __restrict__ bsum, int N) {
  int i = blockIdx.x * 256 + threadIdx.x;
  int v = (i < N) ? deg[i] : 0;
#pragma unroll
  for (int off = 32; off; off >>= 1) v += __shfl_xor(v, off, 64);
  __shared__ int sm[4];
  if ((threadIdx.x & 63) == 0) sm[threadIdx.x >> 6] = v;
  __syncthreads();
  if (threadIdx.x == 0) bsum[blockIdx.x] = sm[0] + sm[1] + sm[2] + sm[3];
}

__global__ __launch_bounds__(512) void scanbsum_k(int* __restrict__ bsum, int nChunks,
                                                  int* __restrict__ row_ptr, int N, int E) {
  __shared__ int sm[512];
  int t = threadIdx.x;
  int v = (t < nChunks) ? bsum[t] : 0;
  sm[t] = v;
  __syncthreads();
  for (int off = 1; off < 512; off <<= 1) {
    int add = (t >= off) ? sm[t - off] : 0;
    __syncthreads();
    sm[t] += add;
    __syncthreads();
  }
  if (t < nChunks) bsum[t] = (t == 0) ? 0 : sm[t - 1];
  if (t == 0) row_ptr[N] = E;
}

__global__ __launch_bounds__(256) void rowptr_k(const int* __restrict__ deg,
                                                const int* __restrict__ boff,
                                                int* __restrict__ row_ptr,
                                                int* __restrict__ cursor, int N) {
  __shared__ int sm[256];
  int t = threadIdx.x;
  int i = blockIdx.x * 256 + t;
  int v = (i < N) ? deg[i] : 0;
  sm[t] = v;
  __syncthreads();
  for (int off = 1; off < 256; off <<= 1) {
    int add = (t >= off) ? sm[t - off] : 0;
    __syncthreads();
    sm[t] += add;
    __syncthreads();
  }
  if (i < N) {
    int excl = sm[t] - v + boff[blockIdx.x];
    row_ptr[i] = excl;
    cursor[i] = excl;
  }
}

// ---------------------------------------------------------------------------
// Multisplit P1: per-chunk bucket counts (bucket-major matrix for scan).
// ---------------------------------------------------------------------------
__global__ __launch_bounds__(256) void pcount_k(const int* __restrict__ ei,
                                                int* __restrict__ counts,
                                                int E, int NBLK) {
  __shared__ int lh[NBMAX];
  int t = threadIdx.x, blk = blockIdx.x;
  if (t < NBMAX) lh[t] = 0;
  __syncthreads();
  int e0 = blk * CHUNK;
  int n = min(CHUNK, E - e0);
  for (int i = t; i < n; i += 256)
    atomicAdd(&lh[((unsigned)ei[E + e0 + i]) >> 12], 1);
  __syncthreads();
  if (t < NBMAX) counts[t * NBLK + blk] = lh[t];
}

// ---------------------------------------------------------------------------
// Multisplit scan: in-place exclusive scan of counts[NBMAX*NBLK], one block.
// ---------------------------------------------------------------------------
__global__ __launch_bounds__(1024) void scanM_k(int* __restrict__ a, int M) {
  __shared__ int sm[1024];
  __shared__ int carry;
  int t = threadIdx.x;
  if (t == 0) carry = 0;
  __syncthreads();
  for (int base = 0; base < M; base += 1024) {
    int v = (base + t < M) ? a[base + t] : 0;
    sm[t] = v;
    __syncthreads();
    for (int off = 1; off < 1024; off <<= 1) {
      int add = (t >= off) ? sm[t - off] : 0;
      __syncthreads();
      sm[t] += add;
      __syncthreads();
    }
    int incl = sm[t];
    int c = carry;
    if (base + t < M) a[base + t] = c + incl - v;
    __syncthreads();
    if (t == 1023) carry = c + incl;
    __syncthreads();
  }
}

// ---------------------------------------------------------------------------
// Multisplit P2: stable partition of (src,dst) into bucket-major ebuf via LDS
// staging. All global writes are contiguous per-bucket bursts (full lines).
// ---------------------------------------------------------------------------
__global__ __launch_bounds__(256) void partition_k(const int* __restrict__ ei,
                                                   const int* __restrict__ bases,
                                                   uint2* __restrict__ ebuf,
                                                   int E, int NBLK) {
  __shared__ uint2 slots[CHUNK];          // 32 KB
  __shared__ int loff[NBMAX], lcur[NBMAX], gadj[NBMAX];
  int t = threadIdx.x, blk = blockIdx.x;
  if (t < NBMAX) lcur[t] = 0;
  __syncthreads();
  int e0 = blk * CHUNK;
  int n = min(CHUNK, E - e0);
  for (int i = t; i < n; i += 256)
    atomicAdd(&lcur[((unsigned)ei[E + e0 + i]) >> 12], 1);
  __syncthreads();
  if (t == 0) {
    int acc = 0;
    for (int b = 0; b < NBMAX; ++b) { loff[b] = acc; acc += lcur[b]; }
  }
  __syncthreads();
  if (t < NBMAX) { gadj[t] = bases[t * NBLK + blk] - loff[t]; lcur[t] = loff[t]; }
  __syncthreads();
  for (int i = t; i < n; i += 256) {
    int s = ei[e0 + i], d = ei[E + e0 + i];
    int pos = atomicAdd(&lcur[((unsigned)d) >> 12], 1);
    slots[pos] = make_uint2((unsigned)s, (unsigned)d);
  }
  __syncthreads();
  for (int i = t; i < n; i += 256) {
    uint2 sd = slots[i];
    ebuf[gadj[sd.y >> 12] + i] = sd;
  }
}

// ---------------------------------------------------------------------------
// Multisplit P3: cursor-fill csr from bucket-ordered ebuf. Chunk swizzle pins
// contiguous chunk ranges (~3 buckets, <1MB of csr) to one XCD so the
// scattered 4B csr writes coalesce in its L2 and reach HBM once.
// ---------------------------------------------------------------------------
__global__ __launch_bounds__(256) void fill2_k(const uint2* __restrict__ ebuf,
                                               int* __restrict__ cursor,
                                               int* __restrict__ csr,
                                               int E, int NBLK) {
  int nPerX = (NBLK + 7) / 8;
  int chunk = (blockIdx.x & 7) * nPerX + (blockIdx.x >> 3);
  if (chunk >= NBLK) return;
  int e0 = chunk * CHUNK;
  int n = min(CHUNK, E - e0);
  for (int i = threadIdx.x; i < n; i += 256) {
    uint2 sd = ebuf[e0 + i];
    int pos = atomicAdd(&cursor[sd.y], 1);
    csr[pos] = (int)sd.x;
  }
}

// ---------------------------------------------------------------------------
// Aggregation layer 1 + fused bias1 + ReLU. Wave per node.
// ---------------------------------------------------------------------------
__global__ __launch_bounds__(256) void agg1_k(const float* __restrict__ xw,
                                              const int* __restrict__ row_ptr,
                                              const int* __restrict__ csr,
                                              const float* __restrict__ b1,
                                              float* __restrict__ agg, int N) {
  int row = (blockIdx.x * 256 + threadIdx.x) >> 6;
  int lane = threadIdx.x & 63;
  if (row >= N) return;
  int start = row_ptr[row], end = row_ptr[row + 1];
  float a0 = 0.f, a1 = 0.f;
  for (int base = start; base < end; base += 64) {
    int myS = (base + lane < end) ? csr[base + lane] : 0;
    int cnt = min(64, end - base);
    int k = 0;
    for (; k + 1 < cnt; k += 2) {
      int s0 = __shfl(myS, k, 64);
      int s1 = __shfl(myS, k + 1, 64);
      a0 += xw[(size_t)s0 * F_HID + lane];
      a1 += xw[(size_t)s1 * F_HID + lane];
    }
    if (k < cnt) a0 += xw[(size_t)__shfl(myS, k, 64) * F_HID + lane];
  }
  agg[(size_t)row * F_HID + lane] = fmaxf(a0 + a1 + b1[lane], 0.f);
}

// ---------------------------------------------------------------------------
// GEMM2: hw[N,40] = h[N,64] @ W2[64,40]   (h already bias'd+ReLU'd)
// ---------------------------------------------------------------------------
__global__ __launch_bounds__(256) void gemm2_k(const float* __restrict__ h,
                                               const float* __restrict__ W2,
                                               float* __restrict__ hw, int N) {
  int wave = (blockIdx.x * 256 + threadIdx.x) >> 6;
  int lane = threadIdx.x & 63;
  int col = lane < F_OUT ? lane : F_OUT - 1;
  int row0 = wave * RB;
  if (row0 >= N) return;

  if (row0 + RB <= N) {
    row0 = __builtin_amdgcn_readfirstlane(row0);
    const float* hr = h + (size_t)row0 * F_HID;
    float acc[RB];
#pragma unroll
    for (int r = 0; r < RB; ++r) acc[r] = 0.f;

    for (int k0 = 0; k0 < F_HID; k0 += 8) {
      float w[8];
#pragma unroll
      for (int kk = 0; kk < 8; ++kk) w[kk] = W2[(k0 + kk) * F_OUT + col];
#pragma unroll
      for (int r = 0; r < RB; ++r) {
        const float* hp = hr + r * F_HID + k0;
#pragma unroll
        for (int kk = 0; kk < 8; ++kk)
          acc[r] = fmaf(hp[kk], w[kk], acc[r]);
      }
    }
    if (lane < F_OUT) {
#pragma unroll
      for (int r = 0; r < RB; ++r)
        hw[(size_t)(row0 + r) * F_OUT + lane] = acc[r];
    }
  } else {
    for (int r = 0; r < RB && row0 + r < N; ++r) {
      const float* hr = h + (size_t)(row0 + r) * F_HID;
      float acc = 0.f;
      for (int k = 0; k < F_HID; ++k) acc = fmaf(hr[k], W2[k * F_OUT + col], acc);
      if (lane < F_OUT) hw[(size_t)(row0 + r) * F_OUT + lane] = acc;
    }
  }
}

// ---------------------------------------------------------------------------
// Aggregation layer 2 fused with +bias2 and log_softmax. Wave per node.
// ---------------------------------------------------------------------------
__global__ __launch_bounds__(256) void agg2_ls_k(const float* __restrict__ hw,
                                                 const int* __restrict__ row_ptr,
                                                 const int* __restrict__ csr,
                                                 const float* __restrict__ b2,
                                                 float* __restrict__ out, int N) {
  int row = (blockIdx.x * 256 + threadIdx.x) >> 6;
  int lane = threadIdx.x & 63;
  if (row >= N) return;
  int col = lane < F_OUT ? lane : F_OUT - 1;
  int start = row_ptr[row], end = row_ptr[row + 1];
  float a0 = 0.f, a1 = 0.f;
  for (int base = start; base < end; base += 64) {
    int myS = (base + lane < end) ? csr[base + lane] : 0;
    int cnt = min(64, end - base);
    int k = 0;
    for (; k + 1 < cnt; k += 2) {
      int s0 = __shfl(myS, k, 64);
      int s1 = __shfl(myS, k + 1, 64);
      a0 += hw[(size_t)s0 * F_OUT + col];
      a1 += hw[(size_t)s1 * F_OUT + col];
    }
    if (k < cnt) a0 += hw[(size_t)__shfl(myS, k, 64) * F_OUT + col];
  }
  float val = 0.f, m = -3.4e38f;
  if (lane < F_OUT) { val = a0 + a1 + b2[lane]; m = val; }
#pragma unroll
  for (int off = 32; off; off >>= 1) m = fmaxf(m, __shfl_xor(m, off, 64));
  float ex = (lane < F_OUT) ? __expf(val - m) : 0.f;
#pragma unroll
  for (int off = 32; off; off >>= 1) ex += __shfl_xor(ex, off, 64);
  float lse = __logf(ex) + m;
  if (lane < F_OUT) out[(size_t)row * F_OUT + lane] = val - lse;
}

// ---------------------------------------------------------------------------
// ws layout (≈59 MB):
//   xw   : N*64 f32 (reused as hw[N,40] after agg1 consumes it)
//   agg1 : N*64 f32 (ALSO aliased as ebuf[E] uint2 during CSR build —
//                    fill2_k consumes ebuf before agg1_k writes agg1)
//   deg : N | row_ptr : N+1 | cursor : N | bsum : 1024 | csr : E
//   counts : NBMAX * NBLK
// ---------------------------------------------------------------------------
extern "C" void kernel_launch(void* const* d_in, const int* in_sizes, int n_in,
                              void* d_out, int out_size, void* d_ws, size_t ws_size,
                              hipStream_t stream) {
  const float* x  = (const float*)d_in[0];
  const int*   ei = (const int*)d_in[1];
  const float* W1 = (const float*)d_in[2];
  const float* b1 = (const float*)d_in[3];
  const float* W2 = (const float*)d_in[4];
  const float* b2 = (const float*)d_in[5];

  int N = in_sizes[0] / F_IN;
  int E = in_sizes[1] / 2;

  float* xw   = (float*)d_ws;
  float* agg1 = xw + (size_t)N * F_HID;
  int* deg     = (int*)(agg1 + (size_t)N * F_HID);
  int* row_ptr = deg + N;
  int* cursor  = row_ptr + N + 1;
  int* bsum    = cursor + N;
  int* csr     = bsum + 1024;
  int* counts  = csr + E;
  uint2* ebuf  = (uint2*)agg1;   // aliased; consumed before agg1 is written
  float* hw = xw;                // reuse after agg1_k
  float* out = (float*)d_out;

  int nChunks = (N + 255) / 256;
  int edgeGrid = (E + 255) / 256;
  int rowsGrid = (N * 64 + 255) / 256;
  int gemmGrid = ((N + RB - 1) / RB * 64 + 255) / 256;
  int NBLK = (E + CHUNK - 1) / CHUNK;

  hipMemsetAsync(deg, 0, (size_t)N * sizeof(int), stream);

  gemm1_k<<<gemmGrid, 256, 0, stream>>>(x, W1, xw, N);

  // per-node degrees -> row_ptr/cursor
  hist_k<<<edgeGrid, 256, 0, stream>>>(ei, deg, E);
  blocksum_k<<<nChunks, 256, 0, stream>>>(deg, bsum, N);
  scanbsum_k<<<1, 512, 0, stream>>>(bsum, nChunks, row_ptr, N, E);
  rowptr_k<<<nChunks, 256, 0, stream>>>(deg, bsum, row_ptr, cursor, N);

  // bucket multisplit -> L2-local csr fill
  pcount_k<<<NBLK, 256, 0, stream>>>(ei, counts, E, NBLK);
  scanM_k<<<1, 1024, 0, stream>>>(counts, NBMAX * NBLK);
  partition_k<<<NBLK, 256, 0, stream>>>(ei, counts, ebuf, E, NBLK);
  fill2_k<<<((NBLK + 7) / 8) * 8, 256, 0, stream>>>(ebuf, cursor, csr, E, NBLK);

  agg1_k<<<rowsGrid, 256, 0, stream>>>(xw, row_ptr, csr, b1, agg1, N);
  gemm2_k<<<gemmGrid, 256, 0, stream>>>(agg1, W2, hw, N);
  agg2_ls_k<<<rowsGrid, 256, 0, stream>>>(hw, row_ptr, csr, b2, out, N);
}

// Round 5
// 475.952 us; speedup vs baseline: 2.1107x; 1.0291x over previous
//
#include <hip/hip_runtime.h>
#include <cstdint>
#include <cstddef>

#define F_IN  128
#define F_HID 64
#define F_OUT 40

#define NBMAX 32    // max dst-buckets (bucket = dst >> 12; N=100k -> 25 used)
#define CHUNK 4096  // edges per partition block

// bf16 <-> f32 helpers (RNE on pack; values are finite)
__device__ __forceinline__ unsigned short f2bf(float f) {
  unsigned u = __float_as_uint(f);
  u += 0x7fffu + ((u >> 16) & 1u);
  return (unsigned short)(u >> 16);
}
__device__ __forceinline__ float bf2f(unsigned short b) {
  return __uint_as_float((unsigned)b << 16);
}

// ---------------------------------------------------------------------------
// GEMM1: xw[N,64](bf16) = x[N,128](f32) @ W1[128,64](f32)
// Block = 64-row x 64-col tile. x tile staged coalesced into padded LDS;
// compute reads are wave-uniform ds_read_b128 broadcasts (no scalar-mem
// serial chain); W1 loads coalesced per-lane, L1-hot after first tile.
// ---------------------------------------------------------------------------
__global__ __launch_bounds__(256) void gemm1_k(const float* __restrict__ x,
                                               const float* __restrict__ W1,
                                               unsigned short* __restrict__ xw, int N) {
  __shared__ float xs[64][132];            // pad 128->132 : 16B-aligned rows
  int t = threadIdx.x;
  int rowBase = blockIdx.x * 64;

  // stage 64x128 f32 tile (2048 float4 slots, coalesced)
  for (int i = t; i < 2048; i += 256) {
    int r = i >> 5, kq = i & 31;
    float4 v = make_float4(0.f, 0.f, 0.f, 0.f);
    if (rowBase + r < N)
      v = *(const float4*)(x + (size_t)(rowBase + r) * F_IN + kq * 4);
    *(float4*)&xs[r][kq * 4] = v;
  }
  __syncthreads();

  int c = t & 63;
  int r0 = (t >> 6) * 16;                  // wave-uniform
  float acc[16];
#pragma unroll
  for (int r = 0; r < 16; ++r) acc[r] = 0.f;

  for (int k = 0; k < F_IN; k += 4) {
    float w0 = W1[(k + 0) * F_HID + c];
    float w1 = W1[(k + 1) * F_HID + c];
    float w2 = W1[(k + 2) * F_HID + c];
    float w3 = W1[(k + 3) * F_HID + c];
#pragma unroll
    for (int r = 0; r < 16; ++r) {
      float4 xv = *(const float4*)&xs[r0 + r][k];   // uniform -> broadcast
      acc[r] = fmaf(xv.x, w0, acc[r]);
      acc[r] = fmaf(xv.y, w1, acc[r]);
      acc[r] = fmaf(xv.z, w2, acc[r]);
      acc[r] = fmaf(xv.w, w3, acc[r]);
    }
  }
#pragma unroll
  for (int r = 0; r < 16; ++r) {
    int row = rowBase + r0 + r;
    if (row < N) xw[(size_t)row * F_HID + c] = f2bf(acc[r]);
  }
}

// ---------------------------------------------------------------------------
// Per-node degree histogram (deg is 400KB -> L2-resident, atomics cheap).
// ---------------------------------------------------------------------------
__global__ __launch_bounds__(256) void hist_k(const int* __restrict__ ei,
                                              int* __restrict__ deg, int E) {
  int e = blockIdx.x * 256 + threadIdx.x;
  if (e < E) atomicAdd(&deg[ei[E + e]], 1);
}

__global__ __launch_bounds__(256) void blocksum_k(const int* __restrict__ deg,
                                                  int* __restrict__ bsum, int N) {
  int i = blockIdx.x * 256 + threadIdx.x;
  int v = (i < N) ? deg[i] : 0;
#pragma unroll
  for (int off = 32; off; off >>= 1) v += __shfl_xor(v, off, 64);
  __shared__ int sm[4];
  if ((threadIdx.x & 63) == 0) sm[threadIdx.x >> 6] = v;
  __syncthreads();
  if (threadIdx.x == 0) bsum[blockIdx.x] = sm[0] + sm[1] + sm[2] + sm[3];
}

__global__ __launch_bounds__(512) void scanbsum_k(int* __restrict__ bsum, int nChunks,
                                                  int* __restrict__ row_ptr, int N, int E) {
  __shared__ int sm[512];
  int t = threadIdx.x;
  int v = (t < nChunks) ? bsum[t] : 0;
  sm[t] = v;
  __syncthreads();
  for (int off = 1; off < 512; off <<= 1) {
    int add = (t >= off) ? sm[t - off] : 0;
    __syncthreads();
    sm[t] += add;
    __syncthreads();
  }
  if (t < nChunks) bsum[t] = (t == 0) ? 0 : sm[t - 1];
  if (t == 0) row_ptr[N] = E;
}

__global__ __launch_bounds__(256) void rowptr_k(const int* __restrict__ deg,
                                                const int* __restrict__ boff,
                                                int* __restrict__ row_ptr,
                                                int* __restrict__ cursor, int N) {
  __shared__ int sm[256];
  int t = threadIdx.x;
  int i = blockIdx.x * 256 + t;
  int v = (i < N) ? deg[i] : 0;
  sm[t] = v;
  __syncthreads();
  for (int off = 1; off < 256; off <<= 1) {
    int add = (t >= off) ? sm[t - off] : 0;
    __syncthreads();
    sm[t] += add;
    __syncthreads();
  }
  if (i < N) {
    int excl = sm[t] - v + boff[blockIdx.x];
    row_ptr[i] = excl;
    cursor[i] = excl;
  }
}

// ---------------------------------------------------------------------------
// Multisplit P1: per-chunk bucket counts (bucket-major matrix for scan).
// ---------------------------------------------------------------------------
__global__ __launch_bounds__(256) void pcount_k(const int* __restrict__ ei,
                                                int* __restrict__ counts,
                                                int E, int NBLK) {
  __shared__ int lh[NBMAX];
  int t = threadIdx.x, blk = blockIdx.x;
  if (t < NBMAX) lh[t] = 0;
  __syncthreads();
  int e0 = blk * CHUNK;
  int n = min(CHUNK, E - e0);
  for (int i = t; i < n; i += 256)
    atomicAdd(&lh[((unsigned)ei[E + e0 + i]) >> 12], 1);
  __syncthreads();
  if (t < NBMAX) counts[t * NBLK + blk] = lh[t];
}

__global__ __launch_bounds__(1024) void scanM_k(int* __restrict__ a, int M) {
  __shared__ int sm[1024];
  __shared__ int carry;
  int t = threadIdx.x;
  if (t == 0) carry = 0;
  __syncthreads();
  for (int base = 0; base < M; base += 1024) {
    int v = (base + t < M) ? a[base + t] : 0;
    sm[t] = v;
    __syncthreads();
    for (int off = 1; off < 1024; off <<= 1) {
      int add = (t >= off) ? sm[t - off] : 0;
      __syncthreads();
      sm[t] += add;
      __syncthreads();
    }
    int incl = sm[t];
    int c = carry;
    if (base + t < M) a[base + t] = c + incl - v;
    __syncthreads();
    if (t == 1023) carry = c + incl;
    __syncthreads();
  }
}

// ---------------------------------------------------------------------------
// Multisplit P2: stable partition of (src,dst) into bucket-major ebuf.
// ---------------------------------------------------------------------------
__global__ __launch_bounds__(256) void partition_k(const int* __restrict__ ei,
                                                   const int* __restrict__ bases,
                                                   uint2* __restrict__ ebuf,
                                                   int E, int NBLK) {
  __shared__ uint2 slots[CHUNK];          // 32 KB
  __shared__ int loff[NBMAX], lcur[NBMAX], gadj[NBMAX];
  int t = threadIdx.x, blk = blockIdx.x;
  if (t < NBMAX) lcur[t] = 0;
  __syncthreads();
  int e0 = blk * CHUNK;
  int n = min(CHUNK, E - e0);
  for (int i = t; i < n; i += 256)
    atomicAdd(&lcur[((unsigned)ei[E + e0 + i]) >> 12], 1);
  __syncthreads();
  if (t == 0) {
    int acc = 0;
    for (int b = 0; b < NBMAX; ++b) { loff[b] = acc; acc += lcur[b]; }
  }
  __syncthreads();
  if (t < NBMAX) { gadj[t] = bases[t * NBLK + blk] - loff[t]; lcur[t] = loff[t]; }
  __syncthreads();
  for (int i = t; i < n; i += 256) {
    int s = ei[e0 + i], d = ei[E + e0 + i];
    int pos = atomicAdd(&lcur[((unsigned)d) >> 12], 1);
    slots[pos] = make_uint2((unsigned)s, (unsigned)d);
  }
  __syncthreads();
  for (int i = t; i < n; i += 256) {
    uint2 sd = slots[i];
    ebuf[gadj[sd.y >> 12] + i] = sd;
  }
}

// ---------------------------------------------------------------------------
// Multisplit P3: cursor-fill csr from bucket-ordered ebuf, XCD-swizzled.
// ---------------------------------------------------------------------------
__global__ __launch_bounds__(256) void fill2_k(const uint2* __restrict__ ebuf,
                                               int* __restrict__ cursor,
                                               int* __restrict__ csr,
                                               int E, int NBLK) {
  int nPerX = (NBLK + 7) / 8;
  int chunk = (blockIdx.x & 7) * nPerX + (blockIdx.x >> 3);
  if (chunk >= NBLK) return;
  int e0 = chunk * CHUNK;
  int n = min(CHUNK, E - e0);
  for (int i = threadIdx.x; i < n; i += 256) {
    uint2 sd = ebuf[e0 + i];
    int pos = atomicAdd(&cursor[sd.y], 1);
    csr[pos] = (int)sd.x;
  }
}

// ---------------------------------------------------------------------------
// Aggregation layer 1 + fused bias1 + ReLU, bf16 in/out:
//   h[n][j] = relu( sum_{s in nbrs(n)} xw[s][j] + b1[j] )
// Each gather reads one aligned 128-B line (64 x bf16).
// ---------------------------------------------------------------------------
__global__ __launch_bounds__(256) void agg1_k(const unsigned short* __restrict__ xw,
                                              const int* __restrict__ row_ptr,
                                              const int* __restrict__ csr,
                                              const float* __restrict__ b1,
                                              unsigned short* __restrict__ h, int N) {
  int row = (blockIdx.x * 256 + threadIdx.x) >> 6;
  int lane = threadIdx.x & 63;
  if (row >= N) return;
  int start = row_ptr[row], end = row_ptr[row + 1];
  float a0 = 0.f, a1 = 0.f;
  for (int base = start; base < end; base += 64) {
    int myS = (base + lane < end) ? csr[base + lane] : 0;
    int cnt = min(64, end - base);
    int k = 0;
    for (; k + 1 < cnt; k += 2) {
      int s0 = __shfl(myS, k, 64);
      int s1 = __shfl(myS, k + 1, 64);
      a0 += bf2f(xw[(size_t)s0 * F_HID + lane]);
      a1 += bf2f(xw[(size_t)s1 * F_HID + lane]);
    }
    if (k < cnt) a0 += bf2f(xw[(size_t)__shfl(myS, k, 64) * F_HID + lane]);
  }
  h[(size_t)row * F_HID + lane] = f2bf(fmaxf(a0 + a1 + b1[lane], 0.f));
}

// ---------------------------------------------------------------------------
// GEMM2: hw[N,64-padded](bf16) = h[N,64](bf16) @ W2[64,40](f32)
// Same LDS-tile structure as gemm1 (cols 40..63 unused, never read back).
// ---------------------------------------------------------------------------
__global__ __launch_bounds__(256) void gemm2_k(const unsigned short* __restrict__ h,
                                               const float* __restrict__ W2,
                                               unsigned short* __restrict__ hw, int N) {
  __shared__ float hs[64][68];             // pad 64->68 : 16B-aligned rows
  int t = threadIdx.x;
  int rowBase = blockIdx.x * 64;

  for (int i = t; i < 1024; i += 256) {    // 64 rows x 16 ushort4 slots
    int r = i >> 4, kq = i & 15;
    float4 fv = make_float4(0.f, 0.f, 0.f, 0.f);
    if (rowBase + r < N) {
      ushort4 uv = *(const ushort4*)(h + (size_t)(rowBase + r) * F_HID + kq * 4);
      fv.x = bf2f(uv.x); fv.y = bf2f(uv.y); fv.z = bf2f(uv.z); fv.w = bf2f(uv.w);
    }
    *(float4*)&hs[r][kq * 4] = fv;
  }
  __syncthreads();

  int c = t & 63;
  int cw = c < F_OUT ? c : F_OUT - 1;
  int r0 = (t >> 6) * 16;
  float acc[16];
#pragma unroll
  for (int r = 0; r < 16; ++r) acc[r] = 0.f;

  for (int k = 0; k < F_HID; k += 4) {
    float w0 = W2[(k + 0) * F_OUT + cw];
    float w1 = W2[(k + 1) * F_OUT + cw];
    float w2 = W2[(k + 2) * F_OUT + cw];
    float w3 = W2[(k + 3) * F_OUT + cw];
#pragma unroll
    for (int r = 0; r < 16; ++r) {
      float4 hv = *(const float4*)&hs[r0 + r][k];
      acc[r] = fmaf(hv.x, w0, acc[r]);
      acc[r] = fmaf(hv.y, w1, acc[r]);
      acc[r] = fmaf(hv.z, w2, acc[r]);
      acc[r] = fmaf(hv.w, w3, acc[r]);
    }
  }
  if (c < F_OUT) {
#pragma unroll
    for (int r = 0; r < 16; ++r) {
      int row = rowBase + r0 + r;
      if (row < N) hw[(size_t)row * F_HID + c] = f2bf(acc[r]);
    }
  }
}

// ---------------------------------------------------------------------------
// Aggregation layer 2 (bf16 gather) fused with +bias2 and log_softmax.
// ---------------------------------------------------------------------------
__global__ __launch_bounds__(256) void agg2_ls_k(const unsigned short* __restrict__ hw,
                                                 const int* __restrict__ row_ptr,
                                                 const int* __restrict__ csr,
                                                 const float* __restrict__ b2,
                                                 float* __restrict__ out, int N) {
  int row = (blockIdx.x * 256 + threadIdx.x) >> 6;
  int lane = threadIdx.x & 63;
  if (row >= N) return;
  int col = lane < F_OUT ? lane : F_OUT - 1;
  int start = row_ptr[row], end = row_ptr[row + 1];
  float a0 = 0.f, a1 = 0.f;
  for (int base = start; base < end; base += 64) {
    int myS = (base + lane < end) ? csr[base + lane] : 0;
    int cnt = min(64, end - base);
    int k = 0;
    for (; k + 1 < cnt; k += 2) {
      int s0 = __shfl(myS, k, 64);
      int s1 = __shfl(myS, k + 1, 64);
      a0 += bf2f(hw[(size_t)s0 * F_HID + col]);
      a1 += bf2f(hw[(size_t)s1 * F_HID + col]);
    }
    if (k < cnt) a0 += bf2f(hw[(size_t)__shfl(myS, k, 64) * F_HID + col]);
  }
  float val = 0.f, m = -3.4e38f;
  if (lane < F_OUT) { val = a0 + a1 + b2[lane]; m = val; }
#pragma unroll
  for (int off = 32; off; off >>= 1) m = fmaxf(m, __shfl_xor(m, off, 64));
  float ex = (lane < F_OUT) ? __expf(val - m) : 0.f;
#pragma unroll
  for (int off = 32; off; off >>= 1) ex += __shfl_xor(ex, off, 64);
  float lse = __logf(ex) + m;
  if (lane < F_OUT) out[(size_t)row * F_OUT + lane] = val - lse;
}

// ---------------------------------------------------------------------------
// ws layout (≈33 MB):
//   regA : xw[N,64] bf16 (12.8 MB) — reused as hw by gemm2 (xw dead then)
//   regB : ebuf[E] uint2 (12.8 MB) — reused as h[N,64] bf16 (ebuf dead then)
//   deg : N | row_ptr : N+1 | cursor : N | bsum : 1024 | csr : E | counts
// ---------------------------------------------------------------------------
extern "C" void kernel_launch(void* const* d_in, const int* in_sizes, int n_in,
                              void* d_out, int out_size, void* d_ws, size_t ws_size,
                              hipStream_t stream) {
  const float* x  = (const float*)d_in[0];
  const int*   ei = (const int*)d_in[1];
  const float* W1 = (const float*)d_in[2];
  const float* b1 = (const float*)d_in[3];
  const float* W2 = (const float*)d_in[4];
  const float* b2 = (const float*)d_in[5];

  int N = in_sizes[0] / F_IN;
  int E = in_sizes[1] / 2;

  char* base = (char*)d_ws;
  size_t szA = (size_t)N * F_HID * sizeof(unsigned short);
  size_t szB = (size_t)E * sizeof(uint2);
  if (szA > szB) szB = szA;
  unsigned short* xw = (unsigned short*)base;
  char* regB = base + ((szA + 255) & ~(size_t)255);
  unsigned short* h  = (unsigned short*)regB;
  uint2* ebuf        = (uint2*)regB;
  int* deg     = (int*)(regB + ((szB + 255) & ~(size_t)255));
  int* row_ptr = deg + N;
  int* cursor  = row_ptr + N + 1;
  int* bsum    = cursor + N;
  int* csr     = bsum + 1024;
  int* counts  = csr + E;
  unsigned short* hw = xw;       // reuse after agg1_k consumed xw
  float* out = (float*)d_out;

  int nChunks  = (N + 255) / 256;
  int edgeGrid = (E + 255) / 256;
  int rowsGrid = (N * 64 + 255) / 256;
  int tileGrid = (N + 63) / 64;
  int NBLK = (E + CHUNK - 1) / CHUNK;

  hipMemsetAsync(deg, 0, (size_t)N * sizeof(int), stream);

  gemm1_k<<<tileGrid, 256, 0, stream>>>(x, W1, xw, N);

  // per-node degrees -> row_ptr/cursor
  hist_k<<<edgeGrid, 256, 0, stream>>>(ei, deg, E);
  blocksum_k<<<nChunks, 256, 0, stream>>>(deg, bsum, N);
  scanbsum_k<<<1, 512, 0, stream>>>(bsum, nChunks, row_ptr, N, E);
  rowptr_k<<<nChunks, 256, 0, stream>>>(deg, bsum, row_ptr, cursor, N);

  // bucket multisplit -> L2-local csr fill
  pcount_k<<<NBLK, 256, 0, stream>>>(ei, counts, E, NBLK);
  scanM_k<<<1, 1024, 0, stream>>>(counts, NBMAX * NBLK);
  partition_k<<<NBLK, 256, 0, stream>>>(ei, counts, ebuf, E, NBLK);
  fill2_k<<<((NBLK + 7) / 8) * 8, 256, 0, stream>>>(ebuf, cursor, csr, E, NBLK);

  agg1_k<<<rowsGrid, 256, 0, stream>>>(xw, row_ptr, csr, b1, h, N);
  gemm2_k<<<tileGrid, 256, 0, stream>>>(h, W2, hw, N);
  agg2_ls_k<<<rowsGrid, 256, 0, stream>>>(hw, row_ptr, csr, b2, out, N);
}

// Round 6
// 432.354 us; speedup vs baseline: 2.3235x; 1.1008x over previous
//
#include <hip/hip_runtime.h>
#include <cstdint>
#include <cstddef>

#define F_IN  128
#define F_HID 64
#define F_OUT 40

#define NBMAX 32    // max dst-buckets (bucket = dst >> 12; N=100k -> 25 used)
#define CHUNK 4096  // edges per partition block

// bf16 <-> f32 helpers (RNE on pack; values are finite)
__device__ __forceinline__ unsigned short f2bf(float f) {
  unsigned u = __float_as_uint(f);
  u += 0x7fffu + ((u >> 16) & 1u);
  return (unsigned short)(u >> 16);
}
__device__ __forceinline__ float bf2f(unsigned short b) {
  return __uint_as_float((unsigned)b << 16);
}
__device__ __forceinline__ float bflo(unsigned u) { return __uint_as_float(u << 16); }
__device__ __forceinline__ float bfhi(unsigned u) { return __uint_as_float(u & 0xffff0000u); }
__device__ __forceinline__ unsigned packbf(float lo, float hi) {
  return (unsigned)f2bf(lo) | ((unsigned)f2bf(hi) << 16);
}

// ---------------------------------------------------------------------------
// GEMM1: xw[N,64](bf16) = x[N,128](f32) @ W1[128,64](f32). 64x64 LDS tile.
// ---------------------------------------------------------------------------
__global__ __launch_bounds__(256) void gemm1_k(const float* __restrict__ x,
                                               const float* __restrict__ W1,
                                               unsigned short* __restrict__ xw, int N) {
  __shared__ float xs[64][132];
  int t = threadIdx.x;
  int rowBase = blockIdx.x * 64;

  for (int i = t; i < 2048; i += 256) {
    int r = i >> 5, kq = i & 31;
    float4 v = make_float4(0.f, 0.f, 0.f, 0.f);
    if (rowBase + r < N)
      v = *(const float4*)(x + (size_t)(rowBase + r) * F_IN + kq * 4);
    *(float4*)&xs[r][kq * 4] = v;
  }
  __syncthreads();

  int c = t & 63;
  int r0 = (t >> 6) * 16;
  float acc[16];
#pragma unroll
  for (int r = 0; r < 16; ++r) acc[r] = 0.f;

  for (int k = 0; k < F_IN; k += 4) {
    float w0 = W1[(k + 0) * F_HID + c];
    float w1 = W1[(k + 1) * F_HID + c];
    float w2 = W1[(k + 2) * F_HID + c];
    float w3 = W1[(k + 3) * F_HID + c];
#pragma unroll
    for (int r = 0; r < 16; ++r) {
      float4 xv = *(const float4*)&xs[r0 + r][k];
      acc[r] = fmaf(xv.x, w0, acc[r]);
      acc[r] = fmaf(xv.y, w1, acc[r]);
      acc[r] = fmaf(xv.z, w2, acc[r]);
      acc[r] = fmaf(xv.w, w3, acc[r]);
    }
  }
#pragma unroll
  for (int r = 0; r < 16; ++r) {
    int row = rowBase + r0 + r;
    if (row < N) xw[(size_t)row * F_HID + c] = f2bf(acc[r]);
  }
}

// ---------------------------------------------------------------------------
// P1 + degree histogram fused: one pass over dst. lh = per-chunk bucket
// counts (bucket-major for the scan); deg = per-node degrees (L2-resident).
// ---------------------------------------------------------------------------
__global__ __launch_bounds__(256) void pcount_k(const int* __restrict__ ei,
                                                int* __restrict__ deg,
                                                int* __restrict__ counts,
                                                int E, int NBLK) {
  __shared__ int lh[NBMAX];
  int t = threadIdx.x, blk = blockIdx.x;
  if (t < NBMAX) lh[t] = 0;
  __syncthreads();
  int e0 = blk * CHUNK;
  int n = min(CHUNK, E - e0);
  for (int i = t; i < n; i += 256) {
    int d = ei[E + e0 + i];
    atomicAdd(&lh[((unsigned)d) >> 12], 1);
    atomicAdd(&deg[d], 1);
  }
  __syncthreads();
  if (t < NBMAX) counts[t * NBLK + blk] = lh[t];
}

// In-place exclusive scan of counts[0..M-1]; writes sentinel counts[M]=total.
__global__ __launch_bounds__(1024) void scanM_k(int* __restrict__ a, int M) {
  __shared__ int sm[1024];
  __shared__ int carry;
  int t = threadIdx.x;
  if (t == 0) carry = 0;
  __syncthreads();
  for (int base = 0; base < M; base += 1024) {
    int v = (base + t < M) ? a[base + t] : 0;
    sm[t] = v;
    __syncthreads();
    for (int off = 1; off < 1024; off <<= 1) {
      int add = (t >= off) ? sm[t - off] : 0;
      __syncthreads();
      sm[t] += add;
      __syncthreads();
    }
    int incl = sm[t];
    int c = carry;
    if (base + t < M) a[base + t] = c + incl - v;
    __syncthreads();
    if (t == 1023) carry = c + incl;
    __syncthreads();
  }
  if (t == 0) a[M] = carry;
}

__global__ __launch_bounds__(256) void blocksum_k(const int* __restrict__ deg,
                                                  int* __restrict__ bsum, int N) {
  int i = blockIdx.x * 256 + threadIdx.x;
  int v = (i < N) ? deg[i] : 0;
#pragma unroll
  for (int off = 32; off; off >>= 1) v += __shfl_xor(v, off, 64);
  __shared__ int sm[4];
  if ((threadIdx.x & 63) == 0) sm[threadIdx.x >> 6] = v;
  __syncthreads();
  if (threadIdx.x == 0) bsum[blockIdx.x] = sm[0] + sm[1] + sm[2] + sm[3];
}

__global__ __launch_bounds__(512) void scanbsum_k(int* __restrict__ bsum, int nChunks,
                                                  int* __restrict__ row_ptr, int N, int E) {
  __shared__ int sm[512];
  int t = threadIdx.x;
  int v = (t < nChunks) ? bsum[t] : 0;
  sm[t] = v;
  __syncthreads();
  for (int off = 1; off < 512; off <<= 1) {
    int add = (t >= off) ? sm[t - off] : 0;
    __syncthreads();
    sm[t] += add;
    __syncthreads();
  }
  if (t < nChunks) bsum[t] = (t == 0) ? 0 : sm[t - 1];
  if (t == 0) row_ptr[N] = E;
}

__global__ __launch_bounds__(256) void rowptr_k(const int* __restrict__ deg,
                                                const int* __restrict__ boff,
                                                int* __restrict__ row_ptr,
                                                int* __restrict__ cursor, int N) {
  __shared__ int sm[256];
  int t = threadIdx.x;
  int i = blockIdx.x * 256 + t;
  int v = (i < N) ? deg[i] : 0;
  sm[t] = v;
  __syncthreads();
  for (int off = 1; off < 256; off <<= 1) {
    int add = (t >= off) ? sm[t - off] : 0;
    __syncthreads();
    sm[t] += add;
    __syncthreads();
  }
  if (i < N) {
    int excl = sm[t] - v + boff[blockIdx.x];
    row_ptr[i] = excl;
    cursor[i] = excl;
  }
}

// ---------------------------------------------------------------------------
// Multisplit P2: stable partition into bucket-major ebuf. Local bucket
// counts come from scanned-counts diffs (sentinel) — single edge pass.
// ---------------------------------------------------------------------------
__global__ __launch_bounds__(256) void partition_k(const int* __restrict__ ei,
                                                   const int* __restrict__ bases,
                                                   uint2* __restrict__ ebuf,
                                                   int E, int NBLK) {
  __shared__ uint2 slots[CHUNK];          // 32 KB
  __shared__ int lcur[NBMAX], gadj[NBMAX];
  int t = threadIdx.x, blk = blockIdx.x;
  int e0 = blk * CHUNK;
  int n = min(CHUNK, E - e0);

  if (t < 64) {                           // first wave: 32-entry prefix scan
    int b = t;
    int cnt = 0, base0 = 0;
    if (b < NBMAX) {
      base0 = bases[b * NBLK + blk];
      cnt = bases[b * NBLK + blk + 1] - base0;   // orig count (excl-scan diff)
    }
    int v = cnt;
#pragma unroll
    for (int off = 1; off < 64; off <<= 1) {
      int u = __shfl_up(v, off, 64);
      if (t >= off) v += u;
    }
    int excl = v - cnt;
    if (b < NBMAX) { lcur[b] = excl; gadj[b] = base0 - excl; }
  }
  __syncthreads();

  for (int i = t; i < n; i += 256) {
    int s = ei[e0 + i], d = ei[E + e0 + i];
    int pos = atomicAdd(&lcur[((unsigned)d) >> 12], 1);
    slots[pos] = make_uint2((unsigned)s, (unsigned)d);
  }
  __syncthreads();
  for (int i = t; i < n; i += 256) {
    uint2 sd = slots[i];
    ebuf[gadj[sd.y >> 12] + i] = sd;
  }
}

// ---------------------------------------------------------------------------
// Multisplit P3: cursor-fill csr from bucket-ordered ebuf, XCD-swizzled.
// ---------------------------------------------------------------------------
__global__ __launch_bounds__(256) void fill2_k(const uint2* __restrict__ ebuf,
                                               int* __restrict__ cursor,
                                               int* __restrict__ csr,
                                               int E, int NBLK) {
  int nPerX = (NBLK + 7) / 8;
  int chunk = (blockIdx.x & 7) * nPerX + (blockIdx.x >> 3);
  if (chunk >= NBLK) return;
  int e0 = chunk * CHUNK;
  int n = min(CHUNK, E - e0);
  for (int i = threadIdx.x; i < n; i += 256) {
    uint2 sd = ebuf[e0 + i];
    int pos = atomicAdd(&cursor[sd.y], 1);
    csr[pos] = (int)sd.x;
  }
}

// ---------------------------------------------------------------------------
// Aggregation layer 1 + fused bias1 + ReLU, 8 edges per gather:
// lane = (slot=l>>3 edge, part=l&7 16-B row segment). One dwordx4 gather
// fetches 8 full 128-B rows; butterfly over slot bits reduces.
// ---------------------------------------------------------------------------
__global__ __launch_bounds__(256) void agg1_k(const unsigned short* __restrict__ xw,
                                              const int* __restrict__ row_ptr,
                                              const int* __restrict__ csr,
                                              const float* __restrict__ b1,
                                              unsigned short* __restrict__ h, int N) {
  int row = (blockIdx.x * 256 + threadIdx.x) >> 6;
  int lane = threadIdx.x & 63;
  if (row >= N) return;
  int slot = lane >> 3, part = lane & 7;
  int start = row_ptr[row], end = row_ptr[row + 1];

  float acc[8];
#pragma unroll
  for (int j = 0; j < 8; ++j) acc[j] = 0.f;

  for (int base = start; base < end; base += 8) {
    int idx = base + slot;
    if (idx < end) {
      int s = csr[idx];
      uint4 v = *(const uint4*)(xw + ((size_t)s << 6) + (part << 3));
      acc[0] += bflo(v.x); acc[1] += bfhi(v.x);
      acc[2] += bflo(v.y); acc[3] += bfhi(v.y);
      acc[4] += bflo(v.z); acc[5] += bfhi(v.z);
      acc[6] += bflo(v.w); acc[7] += bfhi(v.w);
    }
  }
#pragma unroll
  for (int off = 8; off < 64; off <<= 1) {
#pragma unroll
    for (int j = 0; j < 8; ++j) acc[j] += __shfl_xor(acc[j], off, 64);
  }
  if (slot == 0) {
    int c0 = part << 3;
    float4 bA = *(const float4*)(b1 + c0);
    float4 bB = *(const float4*)(b1 + c0 + 4);
    float r0 = fmaxf(acc[0] + bA.x, 0.f), r1 = fmaxf(acc[1] + bA.y, 0.f);
    float r2 = fmaxf(acc[2] + bA.z, 0.f), r3 = fmaxf(acc[3] + bA.w, 0.f);
    float r4 = fmaxf(acc[4] + bB.x, 0.f), r5 = fmaxf(acc[5] + bB.y, 0.f);
    float r6 = fmaxf(acc[6] + bB.z, 0.f), r7 = fmaxf(acc[7] + bB.w, 0.f);
    uint4 o = make_uint4(packbf(r0, r1), packbf(r2, r3), packbf(r4, r5), packbf(r6, r7));
    *(uint4*)(h + ((size_t)row << 6) + c0) = o;
  }
}

// ---------------------------------------------------------------------------
// GEMM2: hw[N,64](bf16) = h[N,64](bf16) @ W2[64,40](f32); cols 40..63 = 0
// (agg2 reads full rows, so the pad must be clean zeros).
// ---------------------------------------------------------------------------
__global__ __launch_bounds__(256) void gemm2_k(const unsigned short* __restrict__ h,
                                               const float* __restrict__ W2,
                                               unsigned short* __restrict__ hw, int N) {
  __shared__ float hs[64][68];
  int t = threadIdx.x;
  int rowBase = blockIdx.x * 64;

  for (int i = t; i < 1024; i += 256) {
    int r = i >> 4, kq = i & 15;
    float4 fv = make_float4(0.f, 0.f, 0.f, 0.f);
    if (rowBase + r < N) {
      ushort4 uv = *(const ushort4*)(h + (size_t)(rowBase + r) * F_HID + kq * 4);
      fv.x = bf2f(uv.x); fv.y = bf2f(uv.y); fv.z = bf2f(uv.z); fv.w = bf2f(uv.w);
    }
    *(float4*)&hs[r][kq * 4] = fv;
  }
  __syncthreads();

  int c = t & 63;
  int cw = c < F_OUT ? c : F_OUT - 1;
  int r0 = (t >> 6) * 16;
  float acc[16];
#pragma unroll
  for (int r = 0; r < 16; ++r) acc[r] = 0.f;

  for (int k = 0; k < F_HID; k += 4) {
    float w0 = W2[(k + 0) * F_OUT + cw];
    float w1 = W2[(k + 1) * F_OUT + cw];
    float w2 = W2[(k + 2) * F_OUT + cw];
    float w3 = W2[(k + 3) * F_OUT + cw];
#pragma unroll
    for (int r = 0; r < 16; ++r) {
      float4 hv = *(const float4*)&hs[r0 + r][k];
      acc[r] = fmaf(hv.x, w0, acc[r]);
      acc[r] = fmaf(hv.y, w1, acc[r]);
      acc[r] = fmaf(hv.z, w2, acc[r]);
      acc[r] = fmaf(hv.w, w3, acc[r]);
    }
  }
#pragma unroll
  for (int r = 0; r < 16; ++r) {
    int row = rowBase + r0 + r;
    if (row < N)
      hw[(size_t)row * F_HID + c] = (c < F_OUT) ? f2bf(acc[r]) : (unsigned short)0;
  }
}

// ---------------------------------------------------------------------------
// Aggregation layer 2 (8-edges-per-gather) + bias2 + log_softmax.
// Cols 0..39 live in parts 0..4 (8 cols/lane).
// ---------------------------------------------------------------------------
__global__ __launch_bounds__(256) void agg2_ls_k(const unsigned short* __restrict__ hw,
                                                 const int* __restrict__ row_ptr,
                                                 const int* __restrict__ csr,
                                                 const float* __restrict__ b2,
                                                 float* __restrict__ out, int N) {
  int row = (blockIdx.x * 256 + threadIdx.x) >> 6;
  int lane = threadIdx.x & 63;
  if (row >= N) return;
  int slot = lane >> 3, part = lane & 7;
  int start = row_ptr[row], end = row_ptr[row + 1];

  float acc[8];
#pragma unroll
  for (int j = 0; j < 8; ++j) acc[j] = 0.f;

  for (int base = start; base < end; base += 8) {
    int idx = base + slot;
    if (idx < end) {
      int s = csr[idx];
      uint4 v = *(const uint4*)(hw + ((size_t)s << 6) + (part << 3));
      acc[0] += bflo(v.x); acc[1] += bfhi(v.x);
      acc[2] += bflo(v.y); acc[3] += bfhi(v.y);
      acc[4] += bflo(v.z); acc[5] += bfhi(v.z);
      acc[6] += bflo(v.w); acc[7] += bfhi(v.w);
    }
  }
#pragma unroll
  for (int off = 8; off < 64; off <<= 1) {
#pragma unroll
    for (int j = 0; j < 8; ++j) acc[j] += __shfl_xor(acc[j], off, 64);
  }

  float vj[8];
  float m = -3.4e38f;
  if (part < 5) {
    int c0 = part << 3;
    float4 bA = *(const float4*)(b2 + c0);
    float4 bB = *(const float4*)(b2 + c0 + 4);
    vj[0] = acc[0] + bA.x; vj[1] = acc[1] + bA.y;
    vj[2] = acc[2] + bA.z; vj[3] = acc[3] + bA.w;
    vj[4] = acc[4] + bB.x; vj[5] = acc[5] + bB.y;
    vj[6] = acc[6] + bB.z; vj[7] = acc[7] + bB.w;
#pragma unroll
    for (int j = 0; j < 8; ++j) m = fmaxf(m, vj[j]);
  }
#pragma unroll
  for (int off = 1; off < 8; off <<= 1) m = fmaxf(m, __shfl_xor(m, off, 64));
  float ex = 0.f;
  if (part < 5) {
#pragma unroll
    for (int j = 0; j < 8; ++j) ex += __expf(vj[j] - m);
  }
#pragma unroll
  for (int off = 1; off < 8; off <<= 1) ex += __shfl_xor(ex, off, 64);
  float lse = __logf(ex) + m;

  if (slot == 0 && part < 5) {
    int c0 = part << 3;
    float* op = out + (size_t)row * F_OUT + c0;
    *(float4*)op = make_float4(vj[0] - lse, vj[1] - lse, vj[2] - lse, vj[3] - lse);
    *(float4*)(op + 4) = make_float4(vj[4] - lse, vj[5] - lse, vj[6] - lse, vj[7] - lse);
  }
}

// ---------------------------------------------------------------------------
// ws layout (≈33 MB):
//   regA : xw[N,64] bf16 — reused as hw by gemm2 (xw dead then)
//   regB : ebuf[E] uint2 — reused as h[N,64] bf16 (ebuf dead then)
//   deg : N | row_ptr : N+1 | cursor : N | bsum : 1024 | csr : E
//   counts : NBMAX*NBLK + 1 (sentinel)
// ---------------------------------------------------------------------------
extern "C" void kernel_launch(void* const* d_in, const int* in_sizes, int n_in,
                              void* d_out, int out_size, void* d_ws, size_t ws_size,
                              hipStream_t stream) {
  const float* x  = (const float*)d_in[0];
  const int*   ei = (const int*)d_in[1];
  const float* W1 = (const float*)d_in[2];
  const float* b1 = (const float*)d_in[3];
  const float* W2 = (const float*)d_in[4];
  const float* b2 = (const float*)d_in[5];

  int N = in_sizes[0] / F_IN;
  int E = in_sizes[1] / 2;

  char* base = (char*)d_ws;
  size_t szA = (size_t)N * F_HID * sizeof(unsigned short);
  size_t szB = (size_t)E * sizeof(uint2);
  if (szA > szB) szB = szA;
  unsigned short* xw = (unsigned short*)base;
  char* regB = base + ((szA + 255) & ~(size_t)255);
  unsigned short* h  = (unsigned short*)regB;
  uint2* ebuf        = (uint2*)regB;
  int* deg     = (int*)(regB + ((szB + 255) & ~(size_t)255));
  int* row_ptr = deg + N;
  int* cursor  = row_ptr + N + 1;
  int* bsum    = cursor + N;
  int* csr     = bsum + 1024;
  int* counts  = csr + E;
  unsigned short* hw = xw;       // reuse after agg1_k consumed xw
  float* out = (float*)d_out;

  int nChunks  = (N + 255) / 256;
  int rowsGrid = (N * 64 + 255) / 256;
  int tileGrid = (N + 63) / 64;
  int NBLK = (E + CHUNK - 1) / CHUNK;

  hipMemsetAsync(deg, 0, (size_t)N * sizeof(int), stream);

  gemm1_k<<<tileGrid, 256, 0, stream>>>(x, W1, xw, N);

  // CSR build: fused bucket-counts + degrees, scans, partition, fill
  pcount_k<<<NBLK, 256, 0, stream>>>(ei, deg, counts, E, NBLK);
  scanM_k<<<1, 1024, 0, stream>>>(counts, NBMAX * NBLK);
  blocksum_k<<<nChunks, 256, 0, stream>>>(deg, bsum, N);
  scanbsum_k<<<1, 512, 0, stream>>>(bsum, nChunks, row_ptr, N, E);
  rowptr_k<<<nChunks, 256, 0, stream>>>(deg, bsum, row_ptr, cursor, N);
  partition_k<<<NBLK, 256, 0, stream>>>(ei, counts, ebuf, E, NBLK);
  fill2_k<<<((NBLK + 7) / 8) * 8, 256, 0, stream>>>(ebuf, cursor, csr, E, NBLK);

  agg1_k<<<rowsGrid, 256, 0, stream>>>(xw, row_ptr, csr, b1, h, N);
  gemm2_k<<<tileGrid, 256, 0, stream>>>(h, W2, hw, N);
  agg2_ls_k<<<rowsGrid, 256, 0, stream>>>(hw, row_ptr, csr, b2, out, N);
}

// Round 7
// 308.180 us; speedup vs baseline: 3.2597x; 1.4029x over previous
//
#include <hip/hip_runtime.h>
#include <cstdint>
#include <cstddef>

#define F_IN  128
#define F_HID 64
#define F_OUT 40

#define BSH   9     // bucket = dst >> 9 (512 nodes/bucket); N=100k -> 196 buckets
#define NBMAX 256   // supports N <= 131072
#define CHUNK 4096  // edges per partition block

// bf16 <-> f32 helpers (RNE on pack; values are finite)
__device__ __forceinline__ unsigned short f2bf(float f) {
  unsigned u = __float_as_uint(f);
  u += 0x7fffu + ((u >> 16) & 1u);
  return (unsigned short)(u >> 16);
}
__device__ __forceinline__ float bf2f(unsigned short b) {
  return __uint_as_float((unsigned)b << 16);
}
__device__ __forceinline__ float bflo(unsigned u) { return __uint_as_float(u << 16); }
__device__ __forceinline__ float bfhi(unsigned u) { return __uint_as_float(u & 0xffff0000u); }
__device__ __forceinline__ unsigned packbf(float lo, float hi) {
  return (unsigned)f2bf(lo) | ((unsigned)f2bf(hi) << 16);
}

// ---------------------------------------------------------------------------
// GEMM1: xw[N,64](bf16) = x[N,128](f32) @ W1[128,64](f32). 64x64 LDS tile.
// ---------------------------------------------------------------------------
__global__ __launch_bounds__(256) void gemm1_k(const float* __restrict__ x,
                                               const float* __restrict__ W1,
                                               unsigned short* __restrict__ xw, int N) {
  __shared__ float xs[64][132];
  int t = threadIdx.x;
  int rowBase = blockIdx.x * 64;

  for (int i = t; i < 2048; i += 256) {
    int r = i >> 5, kq = i & 31;
    float4 v = make_float4(0.f, 0.f, 0.f, 0.f);
    if (rowBase + r < N)
      v = *(const float4*)(x + (size_t)(rowBase + r) * F_IN + kq * 4);
    *(float4*)&xs[r][kq * 4] = v;
  }
  __syncthreads();

  int c = t & 63;
  int r0 = (t >> 6) * 16;
  float acc[16];
#pragma unroll
  for (int r = 0; r < 16; ++r) acc[r] = 0.f;

  for (int k = 0; k < F_IN; k += 4) {
    float w0 = W1[(k + 0) * F_HID + c];
    float w1 = W1[(k + 1) * F_HID + c];
    float w2 = W1[(k + 2) * F_HID + c];
    float w3 = W1[(k + 3) * F_HID + c];
#pragma unroll
    for (int r = 0; r < 16; ++r) {
      float4 xv = *(const float4*)&xs[r0 + r][k];
      acc[r] = fmaf(xv.x, w0, acc[r]);
      acc[r] = fmaf(xv.y, w1, acc[r]);
      acc[r] = fmaf(xv.z, w2, acc[r]);
      acc[r] = fmaf(xv.w, w3, acc[r]);
    }
  }
#pragma unroll
  for (int r = 0; r < 16; ++r) {
    int row = rowBase + r0 + r;
    if (row < N) xw[(size_t)row * F_HID + c] = f2bf(acc[r]);
  }
}

// ---------------------------------------------------------------------------
// P1: per-chunk bucket counts (bucket-major matrix). LDS-only; no global
// atomics. 196 buckets -> few same-address LDS collisions.
// ---------------------------------------------------------------------------
__global__ __launch_bounds__(256) void pcount_k(const int* __restrict__ ei,
                                                int* __restrict__ counts,
                                                int E, int NBLK, int NBUCK) {
  __shared__ int lh[NBMAX];
  int t = threadIdx.x, blk = blockIdx.x;
  lh[t] = 0;
  __syncthreads();
  int e0 = blk * CHUNK;
  int n = min(CHUNK, E - e0);
  for (int i = t; i < n; i += 256)
    atomicAdd(&lh[((unsigned)ei[E + e0 + i]) >> BSH], 1);
  __syncthreads();
  if (t < NBUCK) counts[t * NBLK + blk] = lh[t];
}

// ---------------------------------------------------------------------------
// Hierarchical exclusive scan of counts[0..M-1], sentinel counts[M]=E.
// ---------------------------------------------------------------------------
__global__ __launch_bounds__(256) void scanA_k(const int* __restrict__ a,
                                               int* __restrict__ psum, int M) {
  int t = threadIdx.x;
  int base = blockIdx.x * 2048 + t * 8;
  int s = 0;
#pragma unroll
  for (int j = 0; j < 8; ++j) if (base + j < M) s += a[base + j];
#pragma unroll
  for (int off = 32; off; off >>= 1) s += __shfl_xor(s, off, 64);
  __shared__ int sm[4];
  if ((t & 63) == 0) sm[t >> 6] = s;
  __syncthreads();
  if (t == 0) psum[blockIdx.x] = sm[0] + sm[1] + sm[2] + sm[3];
}

__global__ __launch_bounds__(256) void scanB_k(int* __restrict__ psum, int nb) {
  __shared__ int sm[256];
  int t = threadIdx.x;
  int v = (t < nb) ? psum[t] : 0;
  sm[t] = v;
  __syncthreads();
  for (int off = 1; off < 256; off <<= 1) {
    int add = (t >= off) ? sm[t - off] : 0;
    __syncthreads();
    sm[t] += add;
    __syncthreads();
  }
  if (t < nb) psum[t] = sm[t] - v;     // exclusive
}

__global__ __launch_bounds__(256) void scanC_k(int* __restrict__ a,
                                               const int* __restrict__ psum,
                                               int M, int E) {
  __shared__ int sm[256];
  int t = threadIdx.x;
  int base = blockIdx.x * 2048 + t * 8;
  int v[8];
  int s = 0;
#pragma unroll
  for (int j = 0; j < 8; ++j) {
    v[j] = (base + j < M) ? a[base + j] : 0;
    s += v[j];
  }
  sm[t] = s;
  __syncthreads();
  for (int off = 1; off < 256; off <<= 1) {
    int add = (t >= off) ? sm[t - off] : 0;
    __syncthreads();
    sm[t] += add;
    __syncthreads();
  }
  int run = psum[blockIdx.x] + sm[t] - s;
#pragma unroll
  for (int j = 0; j < 8; ++j) {
    if (base + j < M) a[base + j] = run;
    run += v[j];
  }
  if (blockIdx.x == 0 && t == 0) a[M] = E;   // sentinel
}

// ---------------------------------------------------------------------------
// Multisplit P2: stable partition of (src,dst) into bucket-major ebuf.
// Local bucket counts come from scanned-counts diffs — single edge pass.
// ---------------------------------------------------------------------------
__global__ __launch_bounds__(256) void partition_k(const int* __restrict__ bases,
                                                   const int* __restrict__ ei,
                                                   uint2* __restrict__ ebuf,
                                                   int E, int NBLK, int NBUCK) {
  __shared__ uint2 slots[CHUNK];          // 32 KB
  __shared__ int scn[NBMAX], lcur[NBMAX], gadj[NBMAX];
  int t = threadIdx.x, blk = blockIdx.x;
  int e0 = blk * CHUNK;
  int n = min(CHUNK, E - e0);

  int i0 = t * NBLK + blk;
  int cnt = 0, base0 = 0;
  if (t < NBUCK) {
    base0 = bases[i0];
    cnt = bases[i0 + 1] - base0;          // this (bucket,chunk)'s count
  }
  scn[t] = cnt;
  __syncthreads();
  for (int off = 1; off < 256; off <<= 1) {
    int add = (t >= off) ? scn[t - off] : 0;
    __syncthreads();
    scn[t] += add;
    __syncthreads();
  }
  int excl = scn[t] - cnt;
  if (t < NBUCK) { lcur[t] = excl; gadj[t] = base0 - excl; }
  __syncthreads();

  for (int i = t; i < n; i += 256) {
    int s = ei[e0 + i], d = ei[E + e0 + i];
    int pos = atomicAdd(&lcur[((unsigned)d) >> BSH], 1);
    slots[pos] = make_uint2((unsigned)s, (unsigned)d);
  }
  __syncthreads();
  for (int i = t; i < n; i += 256) {
    uint2 sd = slots[i];
    ebuf[gadj[sd.y >> BSH] + i] = sd;
  }
}

// ---------------------------------------------------------------------------
// Bucket-local CSR build: block b owns nodes [b*512, b*512+512) and edge
// range [S,T) of bucket-major ebuf. LDS histogram + scan -> row_ptr (no
// global deg array / atomics); LDS cursor fill -> csr into a private
// contiguous window (L2-local scattered stores).
// ---------------------------------------------------------------------------
__global__ __launch_bounds__(256) void build_k(const uint2* __restrict__ ebuf,
                                               const int* __restrict__ bases,
                                               int* __restrict__ row_ptr,
                                               int* __restrict__ csr,
                                               int N, int E, int NBLK, int NBUCK) {
  __shared__ int hist[512], excl0[512];
  __shared__ int psc[256];
  int t = threadIdx.x, b = blockIdx.x;
  int nodeBase = b << BSH;
  int S = bases[b * NBLK];
  int T = bases[(b + 1) * NBLK];          // sentinel covers b = NBUCK-1

  hist[t] = 0; hist[t + 256] = 0;
  __syncthreads();
  for (int i = S + t; i < T; i += 256)
    atomicAdd(&hist[ebuf[i].y & 511u], 1);
  __syncthreads();

  int v0 = hist[2 * t], v1 = hist[2 * t + 1];
  int pair = v0 + v1;
  psc[t] = pair;
  __syncthreads();
  for (int off = 1; off < 256; off <<= 1) {
    int add = (t >= off) ? psc[t - off] : 0;
    __syncthreads();
    psc[t] += add;
    __syncthreads();
  }
  int ep = psc[t] - pair;                 // exclusive prefix of pair
  int e0 = ep, e1 = ep + v0;
  excl0[2 * t] = e0; excl0[2 * t + 1] = e1;

  int node0 = nodeBase + 2 * t;
  if (node0 < N) row_ptr[node0] = S + e0;
  if (node0 + 1 < N) row_ptr[node0 + 1] = S + e1;
  if (b == 0 && t == 0) row_ptr[N] = E;

  // reuse hist as cursors
  hist[2 * t] = e0; hist[2 * t + 1] = e1;
  __syncthreads();
  for (int i = S + t; i < T; i += 256) {
    uint2 sd = ebuf[i];
    int pos = atomicAdd(&hist[sd.y & 511u], 1);
    csr[S + pos] = (int)sd.x;
  }
  (void)excl0;
}

// ---------------------------------------------------------------------------
// Aggregation layer 1 + fused bias1 + ReLU, 8 edges per gather:
// lane = (slot=l>>3 edge, part=l&7 16-B row segment). One dwordx4 gather
// fetches 8 full 128-B rows; butterfly over slot bits reduces.
// ---------------------------------------------------------------------------
__global__ __launch_bounds__(256) void agg1_k(const unsigned short* __restrict__ xw,
                                              const int* __restrict__ row_ptr,
                                              const int* __restrict__ csr,
                                              const float* __restrict__ b1,
                                              unsigned short* __restrict__ h, int N) {
  int row = (blockIdx.x * 256 + threadIdx.x) >> 6;
  int lane = threadIdx.x & 63;
  if (row >= N) return;
  int slot = lane >> 3, part = lane & 7;
  int start = row_ptr[row], end = row_ptr[row + 1];

  float acc[8];
#pragma unroll
  for (int j = 0; j < 8; ++j) acc[j] = 0.f;

  for (int base = start; base < end; base += 8) {
    int idx = base + slot;
    if (idx < end) {
      int s = csr[idx];
      uint4 v = *(const uint4*)(xw + ((size_t)s << 6) + (part << 3));
      acc[0] += bflo(v.x); acc[1] += bfhi(v.x);
      acc[2] += bflo(v.y); acc[3] += bfhi(v.y);
      acc[4] += bflo(v.z); acc[5] += bfhi(v.z);
      acc[6] += bflo(v.w); acc[7] += bfhi(v.w);
    }
  }
#pragma unroll
  for (int off = 8; off < 64; off <<= 1) {
#pragma unroll
    for (int j = 0; j < 8; ++j) acc[j] += __shfl_xor(acc[j], off, 64);
  }
  if (slot == 0) {
    int c0 = part << 3;
    float4 bA = *(const float4*)(b1 + c0);
    float4 bB = *(const float4*)(b1 + c0 + 4);
    float r0 = fmaxf(acc[0] + bA.x, 0.f), r1 = fmaxf(acc[1] + bA.y, 0.f);
    float r2 = fmaxf(acc[2] + bA.z, 0.f), r3 = fmaxf(acc[3] + bA.w, 0.f);
    float r4 = fmaxf(acc[4] + bB.x, 0.f), r5 = fmaxf(acc[5] + bB.y, 0.f);
    float r6 = fmaxf(acc[6] + bB.z, 0.f), r7 = fmaxf(acc[7] + bB.w, 0.f);
    uint4 o = make_uint4(packbf(r0, r1), packbf(r2, r3), packbf(r4, r5), packbf(r6, r7));
    *(uint4*)(h + ((size_t)row << 6) + c0) = o;
  }
}

// ---------------------------------------------------------------------------
// GEMM2: hw[N,64](bf16) = h[N,64](bf16) @ W2[64,40](f32); cols 40..63 = 0.
// ---------------------------------------------------------------------------
__global__ __launch_bounds__(256) void gemm2_k(const unsigned short* __restrict__ h,
                                               const float* __restrict__ W2,
                                               unsigned short* __restrict__ hw, int N) {
  __shared__ float hs[64][68];
  int t = threadIdx.x;
  int rowBase = blockIdx.x * 64;

  for (int i = t; i < 1024; i += 256) {
    int r = i >> 4, kq = i & 15;
    float4 fv = make_float4(0.f, 0.f, 0.f, 0.f);
    if (rowBase + r < N) {
      ushort4 uv = *(const ushort4*)(h + (size_t)(rowBase + r) * F_HID + kq * 4);
      fv.x = bf2f(uv.x); fv.y = bf2f(uv.y); fv.z = bf2f(uv.z); fv.w = bf2f(uv.w);
    }
    *(float4*)&hs[r][kq * 4] = fv;
  }
  __syncthreads();

  int c = t & 63;
  int cw = c < F_OUT ? c : F_OUT - 1;
  int r0 = (t >> 6) * 16;
  float acc[16];
#pragma unroll
  for (int r = 0; r < 16; ++r) acc[r] = 0.f;

  for (int k = 0; k < F_HID; k += 4) {
    float w0 = W2[(k + 0) * F_OUT + cw];
    float w1 = W2[(k + 1) * F_OUT + cw];
    float w2 = W2[(k + 2) * F_OUT + cw];
    float w3 = W2[(k + 3) * F_OUT + cw];
#pragma unroll
    for (int r = 0; r < 16; ++r) {
      float4 hv = *(const float4*)&hs[r0 + r][k];
      acc[r] = fmaf(hv.x, w0, acc[r]);
      acc[r] = fmaf(hv.y, w1, acc[r]);
      acc[r] = fmaf(hv.z, w2, acc[r]);
      acc[r] = fmaf(hv.w, w3, acc[r]);
    }
  }
#pragma unroll
  for (int r = 0; r < 16; ++r) {
    int row = rowBase + r0 + r;
    if (row < N)
      hw[(size_t)row * F_HID + c] = (c < F_OUT) ? f2bf(acc[r]) : (unsigned short)0;
  }
}

// ---------------------------------------------------------------------------
// Aggregation layer 2 (8-edges-per-gather) + bias2 + log_softmax.
// ---------------------------------------------------------------------------
__global__ __launch_bounds__(256) void agg2_ls_k(const unsigned short* __restrict__ hw,
                                                 const int* __restrict__ row_ptr,
                                                 const int* __restrict__ csr,
                                                 const float* __restrict__ b2,
                                                 float* __restrict__ out, int N) {
  int row = (blockIdx.x * 256 + threadIdx.x) >> 6;
  int lane = threadIdx.x & 63;
  if (row >= N) return;
  int slot = lane >> 3, part = lane & 7;
  int start = row_ptr[row], end = row_ptr[row + 1];

  float acc[8];
#pragma unroll
  for (int j = 0; j < 8; ++j) acc[j] = 0.f;

  for (int base = start; base < end; base += 8) {
    int idx = base + slot;
    if (idx < end) {
      int s = csr[idx];
      uint4 v = *(const uint4*)(hw + ((size_t)s << 6) + (part << 3));
      acc[0] += bflo(v.x); acc[1] += bfhi(v.x);
      acc[2] += bflo(v.y); acc[3] += bfhi(v.y);
      acc[4] += bflo(v.z); acc[5] += bfhi(v.z);
      acc[6] += bflo(v.w); acc[7] += bfhi(v.w);
    }
  }
#pragma unroll
  for (int off = 8; off < 64; off <<= 1) {
#pragma unroll
    for (int j = 0; j < 8; ++j) acc[j] += __shfl_xor(acc[j], off, 64);
  }

  float vj[8];
  float m = -3.4e38f;
  if (part < 5) {
    int c0 = part << 3;
    float4 bA = *(const float4*)(b2 + c0);
    float4 bB = *(const float4*)(b2 + c0 + 4);
    vj[0] = acc[0] + bA.x; vj[1] = acc[1] + bA.y;
    vj[2] = acc[2] + bA.z; vj[3] = acc[3] + bA.w;
    vj[4] = acc[4] + bB.x; vj[5] = acc[5] + bB.y;
    vj[6] = acc[6] + bB.z; vj[7] = acc[7] + bB.w;
#pragma unroll
    for (int j = 0; j < 8; ++j) m = fmaxf(m, vj[j]);
  }
#pragma unroll
  for (int off = 1; off < 8; off <<= 1) m = fmaxf(m, __shfl_xor(m, off, 64));
  float ex = 0.f;
  if (part < 5) {
#pragma unroll
    for (int j = 0; j < 8; ++j) ex += __expf(vj[j] - m);
  }
#pragma unroll
  for (int off = 1; off < 8; off <<= 1) ex += __shfl_xor(ex, off, 64);
  float lse = __logf(ex) + m;

  if (slot == 0 && part < 5) {
    int c0 = part << 3;
    float* op = out + (size_t)row * F_OUT + c0;
    *(float4*)op = make_float4(vj[0] - lse, vj[1] - lse, vj[2] - lse, vj[3] - lse);
    *(float4*)(op + 4) = make_float4(vj[4] - lse, vj[5] - lse, vj[6] - lse, vj[7] - lse);
  }
}

// ---------------------------------------------------------------------------
// ws layout (≈45 MB):
//   regA : xw[N,64] bf16 — reused as hw by gemm2 (xw dead then)
//   regB : ebuf[E] uint2 — reused as h[N,64] bf16 (ebuf dead then)
//   row_ptr : N+1 | csr : E | counts : NBUCK*NBLK+1 | psum : 64
// ---------------------------------------------------------------------------
extern "C" void kernel_launch(void* const* d_in, const int* in_sizes, int n_in,
                              void* d_out, int out_size, void* d_ws, size_t ws_size,
                              hipStream_t stream) {
  const float* x  = (const float*)d_in[0];
  const int*   ei = (const int*)d_in[1];
  const float* W1 = (const float*)d_in[2];
  const float* b1 = (const float*)d_in[3];
  const float* W2 = (const float*)d_in[4];
  const float* b2 = (const float*)d_in[5];

  int N = in_sizes[0] / F_IN;
  int E = in_sizes[1] / 2;

  char* base = (char*)d_ws;
  size_t szA = (size_t)N * F_HID * sizeof(unsigned short);
  size_t szB = (size_t)E * sizeof(uint2);
  if (szA > szB) szB = szA;
  unsigned short* xw = (unsigned short*)base;
  char* regB = base + ((szA + 255) & ~(size_t)255);
  unsigned short* h  = (unsigned short*)regB;
  uint2* ebuf        = (uint2*)regB;
  int* row_ptr = (int*)(regB + ((szB + 255) & ~(size_t)255));
  int* csr     = row_ptr + N + 1;
  int* counts  = csr + E;
  unsigned short* hw = xw;       // reuse after agg1_k consumed xw
  float* out = (float*)d_out;

  int rowsGrid = (N * 64 + 255) / 256;
  int tileGrid = (N + 63) / 64;
  int NBLK  = (E + CHUNK - 1) / CHUNK;
  int NBUCK = (N + 511) >> BSH;
  int M = NBUCK * NBLK;
  int* psum = counts + M + 1;
  int scanBlocks = (M + 2047) / 2048;

  gemm1_k<<<tileGrid, 256, 0, stream>>>(x, W1, xw, N);

  // CSR build: bucket counts -> hierarchical scan -> partition -> local build
  pcount_k<<<NBLK, 256, 0, stream>>>(ei, counts, E, NBLK, NBUCK);
  scanA_k<<<scanBlocks, 256, 0, stream>>>(counts, psum, M);
  scanB_k<<<1, 256, 0, stream>>>(psum, scanBlocks);
  scanC_k<<<scanBlocks, 256, 0, stream>>>(counts, psum, M, E);
  partition_k<<<NBLK, 256, 0, stream>>>(counts, ei, ebuf, E, NBLK, NBUCK);
  build_k<<<NBUCK, 256, 0, stream>>>(ebuf, counts, row_ptr, csr, N, E, NBLK, NBUCK);

  agg1_k<<<rowsGrid, 256, 0, stream>>>(xw, row_ptr, csr, b1, h, N);
  gemm2_k<<<tileGrid, 256, 0, stream>>>(h, W2, hw, N);
  agg2_ls_k<<<rowsGrid, 256, 0, stream>>>(hw, row_ptr, csr, b2, out, N);
}

// Round 8
// 302.595 us; speedup vs baseline: 3.3199x; 1.0185x over previous
//
#include <hip/hip_runtime.h>
#include <cstdint>
#include <cstddef>

#define F_IN  128
#define F_HID 64
#define F_OUT 40

#define BSH   9     // bucket = dst >> 9 (512 nodes/bucket)
#define NBMAX 256   // supports N <= 131072
#define CHUNK 4096  // edges per partition block

typedef __attribute__((ext_vector_type(8))) short short8;   // 8 bf16 = 4 VGPR
typedef __attribute__((ext_vector_type(4))) float f32x4;    // MFMA C/D

// bf16 <-> f32 helpers (RNE on pack; values are finite)
__device__ __forceinline__ unsigned short f2bf(float f) {
  unsigned u = __float_as_uint(f);
  u += 0x7fffu + ((u >> 16) & 1u);
  return (unsigned short)(u >> 16);
}
__device__ __forceinline__ float bf2f(unsigned short b) {
  return __uint_as_float((unsigned)b << 16);
}
__device__ __forceinline__ float bflo(unsigned u) { return __uint_as_float(u << 16); }
__device__ __forceinline__ float bfhi(unsigned u) { return __uint_as_float(u & 0xffff0000u); }
__device__ __forceinline__ unsigned packbf(float lo, float hi) {
  return (unsigned)f2bf(lo) | ((unsigned)f2bf(hi) << 16);
}

// ---------------------------------------------------------------------------
// Pre-swizzle W1/W2 into MFMA B-fragment lane order (bf16), one tiny block.
// B-frag (16x16x32): lane holds B^T[n=lane&15][k=(lane>>4)*8+j], j=0..7.
// w1s: ct(4) x ks(4) frags of 512; w2s: ct(3) x ks(2) frags, n>=40 -> 0.
// ---------------------------------------------------------------------------
__global__ __launch_bounds__(256) void wcvt_k(const float* __restrict__ W1,
                                              const float* __restrict__ W2,
                                              unsigned short* __restrict__ w1s,
                                              unsigned short* __restrict__ w2s) {
  int t = threadIdx.x;
  for (int i = t; i < 8192; i += 256) {
    int f = i >> 9, r = i & 511;
    int lane = r >> 3, j = r & 7;
    int ct = f >> 2, ks = f & 3;
    int n = ct * 16 + (lane & 15);
    int k = ks * 32 + (lane >> 4) * 8 + j;
    w1s[i] = f2bf(W1[k * F_HID + n]);
  }
  for (int i = t; i < 3072; i += 256) {
    int f = i >> 9, r = i & 511;
    int lane = r >> 3, j = r & 7;
    int ct = f >> 1, ks = f & 1;
    int n = ct * 16 + (lane & 15);
    int k = ks * 32 + (lane >> 4) * 8 + j;
    w2s[i] = (n < F_OUT) ? f2bf(W2[k * F_OUT + n]) : (unsigned short)0;
  }
}

// ---------------------------------------------------------------------------
// GEMM1 (MFMA): xw[N,64](bf16) = x[N,128](f32) @ W1. Wave = 16 rows, no LDS.
// A-frags straight from global (coalesced 32B/lane) + inline cvt; B-frags
// from pre-swizzled L2-hot w1s. 16 x mfma_f32_16x16x32_bf16 per wave.
// ---------------------------------------------------------------------------
__global__ __launch_bounds__(256) void gemm1_k(const float* __restrict__ x,
                                               const float* __restrict__ W1,
                                               const unsigned short* __restrict__ w1s,
                                               unsigned short* __restrict__ xw, int N) {
  int lane = threadIdx.x & 63;
  int wid  = (blockIdx.x * 256 + threadIdx.x) >> 6;
  int row0 = wid * 16;
  if (row0 >= N) return;
  int m = lane & 15, q = lane >> 4;

  if (row0 + 16 <= N) {
    short8 b[16];
#pragma unroll
    for (int f = 0; f < 16; ++f)
      b[f] = *(const short8*)(w1s + f * 512 + lane * 8);

    short8 a[4];
#pragma unroll
    for (int ks = 0; ks < 4; ++ks) {
      const float* xp = x + (size_t)(row0 + m) * F_IN + ks * 32 + q * 8;
      float4 v0 = *(const float4*)xp;
      float4 v1 = *(const float4*)(xp + 4);
      short8 t;
      t[0] = (short)f2bf(v0.x); t[1] = (short)f2bf(v0.y);
      t[2] = (short)f2bf(v0.z); t[3] = (short)f2bf(v0.w);
      t[4] = (short)f2bf(v1.x); t[5] = (short)f2bf(v1.y);
      t[6] = (short)f2bf(v1.z); t[7] = (short)f2bf(v1.w);
      a[ks] = t;
    }

    f32x4 z = {0.f, 0.f, 0.f, 0.f};
    f32x4 acc[4] = {z, z, z, z};
#pragma unroll
    for (int ct = 0; ct < 4; ++ct)
#pragma unroll
      for (int ks = 0; ks < 4; ++ks)
        acc[ct] = __builtin_amdgcn_mfma_f32_16x16x32_bf16(a[ks], b[ct * 4 + ks],
                                                          acc[ct], 0, 0, 0);
#pragma unroll
    for (int ct = 0; ct < 4; ++ct)
#pragma unroll
      for (int r = 0; r < 4; ++r) {
        int row = row0 + q * 4 + r;                 // D: col=lane&15, row=q*4+reg
        xw[(size_t)row * F_HID + ct * 16 + m] = f2bf(acc[ct][r]);
      }
  } else {
    for (int r = 0; r < 16 && row0 + r < N; ++r) { // tail: col = lane
      const float* xr = x + (size_t)(row0 + r) * F_IN;
      float s = 0.f;
      for (int k = 0; k < F_IN; ++k) s = fmaf(xr[k], W1[k * F_HID + lane], s);
      xw[(size_t)(row0 + r) * F_HID + lane] = f2bf(s);
    }
  }
}

// ---------------------------------------------------------------------------
// P1: per-chunk bucket counts (bucket-major matrix). LDS-only.
// ---------------------------------------------------------------------------
__global__ __launch_bounds__(256) void pcount_k(const int* __restrict__ ei,
                                                int* __restrict__ counts,
                                                int E, int NBLK, int NBUCK) {
  __shared__ int lh[NBMAX];
  int t = threadIdx.x, blk = blockIdx.x;
  lh[t] = 0;
  __syncthreads();
  int e0 = blk * CHUNK;
  int n = min(CHUNK, E - e0);
  for (int i = t; i < n; i += 256)
    atomicAdd(&lh[((unsigned)ei[E + e0 + i]) >> BSH], 1);
  __syncthreads();
  if (t < NBUCK) counts[t * NBLK + blk] = lh[t];
}

// ---------------------------------------------------------------------------
// Hierarchical exclusive scan of counts[0..M-1], sentinel counts[M]=E.
// ---------------------------------------------------------------------------
__global__ __launch_bounds__(256) void scanA_k(const int* __restrict__ a,
                                               int* __restrict__ psum, int M) {
  int t = threadIdx.x;
  int base = blockIdx.x * 2048 + t * 8;
  int s = 0;
#pragma unroll
  for (int j = 0; j < 8; ++j) if (base + j < M) s += a[base + j];
#pragma unroll
  for (int off = 32; off; off >>= 1) s += __shfl_xor(s, off, 64);
  __shared__ int sm[4];
  if ((t & 63) == 0) sm[t >> 6] = s;
  __syncthreads();
  if (t == 0) psum[blockIdx.x] = sm[0] + sm[1] + sm[2] + sm[3];
}

__global__ __launch_bounds__(256) void scanB_k(int* __restrict__ psum, int nb) {
  __shared__ int sm[256];
  int t = threadIdx.x;
  int v = (t < nb) ? psum[t] : 0;
  sm[t] = v;
  __syncthreads();
  for (int off = 1; off < 256; off <<= 1) {
    int add = (t >= off) ? sm[t - off] : 0;
    __syncthreads();
    sm[t] += add;
    __syncthreads();
  }
  if (t < nb) psum[t] = sm[t] - v;     // exclusive
}

__global__ __launch_bounds__(256) void scanC_k(int* __restrict__ a,
                                               const int* __restrict__ psum,
                                               int M, int E) {
  __shared__ int sm[256];
  int t = threadIdx.x;
  int base = blockIdx.x * 2048 + t * 8;
  int v[8];
  int s = 0;
#pragma unroll
  for (int j = 0; j < 8; ++j) {
    v[j] = (base + j < M) ? a[base + j] : 0;
    s += v[j];
  }
  sm[t] = s;
  __syncthreads();
  for (int off = 1; off < 256; off <<= 1) {
    int add = (t >= off) ? sm[t - off] : 0;
    __syncthreads();
    sm[t] += add;
    __syncthreads();
  }
  int run = psum[blockIdx.x] + sm[t] - s;
#pragma unroll
  for (int j = 0; j < 8; ++j) {
    if (base + j < M) a[base + j] = run;
    run += v[j];
  }
  if (blockIdx.x == 0 && t == 0) a[M] = E;   // sentinel
}

// ---------------------------------------------------------------------------
// Multisplit P2: stable partition of (src,dst) into bucket-major ebuf.
// ---------------------------------------------------------------------------
__global__ __launch_bounds__(256) void partition_k(const int* __restrict__ bases,
                                                   const int* __restrict__ ei,
                                                   uint2* __restrict__ ebuf,
                                                   int E, int NBLK, int NBUCK) {
  __shared__ uint2 slots[CHUNK];          // 32 KB
  __shared__ int scn[NBMAX], lcur[NBMAX], gadj[NBMAX];
  int t = threadIdx.x, blk = blockIdx.x;
  int e0 = blk * CHUNK;
  int n = min(CHUNK, E - e0);

  int i0 = t * NBLK + blk;
  int cnt = 0, base0 = 0;
  if (t < NBUCK) {
    base0 = bases[i0];
    cnt = bases[i0 + 1] - base0;
  }
  scn[t] = cnt;
  __syncthreads();
  for (int off = 1; off < 256; off <<= 1) {
    int add = (t >= off) ? scn[t - off] : 0;
    __syncthreads();
    scn[t] += add;
    __syncthreads();
  }
  int excl = scn[t] - cnt;
  if (t < NBUCK) { lcur[t] = excl; gadj[t] = base0 - excl; }
  __syncthreads();

  for (int i = t; i < n; i += 256) {
    int s = ei[e0 + i], d = ei[E + e0 + i];
    int pos = atomicAdd(&lcur[((unsigned)d) >> BSH], 1);
    slots[pos] = make_uint2((unsigned)s, (unsigned)d);
  }
  __syncthreads();
  for (int i = t; i < n; i += 256) {
    uint2 sd = slots[i];
    ebuf[gadj[sd.y >> BSH] + i] = sd;
  }
}

// ---------------------------------------------------------------------------
// Bucket-local CSR build: LDS histogram + scan -> row_ptr; LDS cursor fill.
// ---------------------------------------------------------------------------
__global__ __launch_bounds__(256) void build_k(const uint2* __restrict__ ebuf,
                                               const int* __restrict__ bases,
                                               int* __restrict__ row_ptr,
                                               int* __restrict__ csr,
                                               int N, int E, int NBLK, int NBUCK) {
  __shared__ int hist[512];
  __shared__ int psc[256];
  int t = threadIdx.x, b = blockIdx.x;
  int nodeBase = b << BSH;
  int S = bases[b * NBLK];
  int T = bases[(b + 1) * NBLK];

  hist[t] = 0; hist[t + 256] = 0;
  __syncthreads();
  for (int i = S + t; i < T; i += 256)
    atomicAdd(&hist[ebuf[i].y & 511u], 1);
  __syncthreads();

  int v0 = hist[2 * t], v1 = hist[2 * t + 1];
  int pair = v0 + v1;
  psc[t] = pair;
  __syncthreads();
  for (int off = 1; off < 256; off <<= 1) {
    int add = (t >= off) ? psc[t - off] : 0;
    __syncthreads();
    psc[t] += add;
    __syncthreads();
  }
  int ep = psc[t] - pair;
  int e0 = ep, e1 = ep + v0;

  int node0 = nodeBase + 2 * t;
  if (node0 < N) row_ptr[node0] = S + e0;
  if (node0 + 1 < N) row_ptr[node0 + 1] = S + e1;
  if (b == 0 && t == 0) row_ptr[N] = E;

  hist[2 * t] = e0; hist[2 * t + 1] = e1;   // reuse as cursors
  __syncthreads();
  for (int i = S + t; i < T; i += 256) {
    uint2 sd = ebuf[i];
    int pos = atomicAdd(&hist[sd.y & 511u], 1);
    csr[S + pos] = (int)sd.x;
  }
}

// ---------------------------------------------------------------------------
// Aggregation layer 1 + bias1 + ReLU. 4 edges/iter: slot=lane>>4 edge,
// part=lane&15 owns 4 cols (8 B). Gathers are full 128-B rows per slot
// group; slot-butterfly is 2 levels x 4 accs.
// ---------------------------------------------------------------------------
__global__ __launch_bounds__(256) void agg1_k(const unsigned short* __restrict__ xw,
                                              const int* __restrict__ row_ptr,
                                              const int* __restrict__ csr,
                                              const float* __restrict__ b1,
                                              unsigned short* __restrict__ h, int N) {
  int row = (blockIdx.x * 256 + threadIdx.x) >> 6;
  int lane = threadIdx.x & 63;
  if (row >= N) return;
  int slot = lane >> 4, part = lane & 15;
  int start = row_ptr[row], end = row_ptr[row + 1];

  float a0 = 0.f, a1 = 0.f, a2 = 0.f, a3 = 0.f;
  for (int base = start; base < end; base += 4) {
    int idx = base + slot;
    if (idx < end) {
      int s = csr[idx];
      uint2 v = *(const uint2*)(xw + ((size_t)s << 6) + (part << 2));
      a0 += bflo(v.x); a1 += bfhi(v.x);
      a2 += bflo(v.y); a3 += bfhi(v.y);
    }
  }
#pragma unroll
  for (int off = 16; off < 64; off <<= 1) {
    a0 += __shfl_xor(a0, off, 64);
    a1 += __shfl_xor(a1, off, 64);
    a2 += __shfl_xor(a2, off, 64);
    a3 += __shfl_xor(a3, off, 64);
  }
  if (slot == 0) {
    int c0 = part << 2;
    float4 bb = *(const float4*)(b1 + c0);
    float r0 = fmaxf(a0 + bb.x, 0.f), r1 = fmaxf(a1 + bb.y, 0.f);
    float r2 = fmaxf(a2 + bb.z, 0.f), r3 = fmaxf(a3 + bb.w, 0.f);
    uint2 o = make_uint2(packbf(r0, r1), packbf(r2, r3));
    *(uint2*)(h + ((size_t)row << 6) + c0) = o;
  }
}

// ---------------------------------------------------------------------------
// GEMM2 (MFMA): hw[N,64](bf16) = h[N,64](bf16) @ W2[64,40]; cols 40..63 = 0.
// Wave = 16 rows; A-frags are raw b128 loads of h; 6 MFMA per wave.
// ---------------------------------------------------------------------------
__global__ __launch_bounds__(256) void gemm2_k(const unsigned short* __restrict__ h,
                                               const float* __restrict__ W2,
                                               const unsigned short* __restrict__ w2s,
                                               unsigned short* __restrict__ hw, int N) {
  int lane = threadIdx.x & 63;
  int wid  = (blockIdx.x * 256 + threadIdx.x) >> 6;
  int row0 = wid * 16;
  if (row0 >= N) return;
  int m = lane & 15, q = lane >> 4;

  if (row0 + 16 <= N) {
    short8 b[6];
#pragma unroll
    for (int f = 0; f < 6; ++f)
      b[f] = *(const short8*)(w2s + f * 512 + lane * 8);

    short8 a[2];
#pragma unroll
    for (int ks = 0; ks < 2; ++ks)
      a[ks] = *(const short8*)(h + (size_t)(row0 + m) * F_HID + ks * 32 + q * 8);

    f32x4 z = {0.f, 0.f, 0.f, 0.f};
    f32x4 acc[3] = {z, z, z};
#pragma unroll
    for (int ct = 0; ct < 3; ++ct)
#pragma unroll
      for (int ks = 0; ks < 2; ++ks)
        acc[ct] = __builtin_amdgcn_mfma_f32_16x16x32_bf16(a[ks], b[ct * 2 + ks],
                                                          acc[ct], 0, 0, 0);
#pragma unroll
    for (int ct = 0; ct < 3; ++ct)
#pragma unroll
      for (int r = 0; r < 4; ++r) {
        int row = row0 + q * 4 + r;
        int c = ct * 16 + m;
        hw[(size_t)row * F_HID + c] = (c < F_OUT) ? f2bf(acc[ct][r]) : (unsigned short)0;
      }
#pragma unroll
    for (int r = 0; r < 4; ++r) {
      int row = row0 + q * 4 + r;
      hw[(size_t)row * F_HID + 48 + m] = 0;
    }
  } else {
    for (int r = 0; r < 16 && row0 + r < N; ++r) {   // tail: col = lane
      const unsigned short* hr = h + (size_t)(row0 + r) * F_HID;
      float s = 0.f;
      if (lane < F_OUT)
        for (int k = 0; k < F_HID; ++k) s = fmaf(bf2f(hr[k]), W2[k * F_OUT + lane], s);
      hw[(size_t)(row0 + r) * F_HID + lane] =
          (lane < F_OUT) ? f2bf(s) : (unsigned short)0;
    }
  }
}

// ---------------------------------------------------------------------------
// Aggregation layer 2 (4 edges/iter) + bias2 + log_softmax.
// parts 0..9 hold cols 0..39; softmax reduces over the low-4 lane bits.
// ---------------------------------------------------------------------------
__global__ __launch_bounds__(256) void agg2_ls_k(const unsigned short* __restrict__ hw,
                                                 const int* __restrict__ row_ptr,
                                                 const int* __restrict__ csr,
                                                 const float* __restrict__ b2,
                                                 float* __restrict__ out, int N) {
  int row = (blockIdx.x * 256 + threadIdx.x) >> 6;
  int lane = threadIdx.x & 63;
  if (row >= N) return;
  int slot = lane >> 4, part = lane & 15;
  int start = row_ptr[row], end = row_ptr[row + 1];

  float a0 = 0.f, a1 = 0.f, a2 = 0.f, a3 = 0.f;
  for (int base = start; base < end; base += 4) {
    int idx = base + slot;
    if (idx < end) {
      int s = csr[idx];
      uint2 v = *(const uint2*)(hw + ((size_t)s << 6) + (part << 2));
      a0 += bflo(v.x); a1 += bfhi(v.x);
      a2 += bflo(v.y); a3 += bfhi(v.y);
    }
  }
#pragma unroll
  for (int off = 16; off < 64; off <<= 1) {
    a0 += __shfl_xor(a0, off, 64);
    a1 += __shfl_xor(a1, off, 64);
    a2 += __shfl_xor(a2, off, 64);
    a3 += __shfl_xor(a3, off, 64);
  }

  bool valid = (part < 10);                 // cols part*4 .. part*4+3 < 40
  float v0 = 0.f, v1 = 0.f, v2 = 0.f, v3 = 0.f;
  float mx = -3.4e38f;
  if (valid) {
    int c0 = part << 2;
    float4 bb = *(const float4*)(b2 + c0);
    v0 = a0 + bb.x; v1 = a1 + bb.y; v2 = a2 + bb.z; v3 = a3 + bb.w;
    mx = fmaxf(fmaxf(v0, v1), fmaxf(v2, v3));
  }
#pragma unroll
  for (int off = 1; off < 16; off <<= 1) mx = fmaxf(mx, __shfl_xor(mx, off, 64));
  float ex = 0.f;
  if (valid)
    ex = __expf(v0 - mx) + __expf(v1 - mx) + __expf(v2 - mx) + __expf(v3 - mx);
#pragma unroll
  for (int off = 1; off < 16; off <<= 1) ex += __shfl_xor(ex, off, 64);
  float lse = __logf(ex) + mx;

  if (slot == 0 && valid) {
    int c0 = part << 2;
    *(float4*)(out + (size_t)row * F_OUT + c0) =
        make_float4(v0 - lse, v1 - lse, v2 - lse, v3 - lse);
  }
}

// ---------------------------------------------------------------------------
// ws layout (≈45 MB):
//   regA : xw[N,64] bf16 — reused as hw by gemm2 (xw dead then)
//   regB : ebuf[E] uint2 — reused as h[N,64] bf16 (ebuf dead then)
//   row_ptr : N+1 | csr : E | counts : M+1 | psum : 64 | w1s : 8192 | w2s : 3072
// ---------------------------------------------------------------------------
extern "C" void kernel_launch(void* const* d_in, const int* in_sizes, int n_in,
                              void* d_out, int out_size, void* d_ws, size_t ws_size,
                              hipStream_t stream) {
  const float* x  = (const float*)d_in[0];
  const int*   ei = (const int*)d_in[1];
  const float* W1 = (const float*)d_in[2];
  const float* b1 = (const float*)d_in[3];
  const float* W2 = (const float*)d_in[4];
  const float* b2 = (const float*)d_in[5];

  int N = in_sizes[0] / F_IN;
  int E = in_sizes[1] / 2;

  char* base = (char*)d_ws;
  size_t szA = (size_t)N * F_HID * sizeof(unsigned short);
  size_t szB = (size_t)E * sizeof(uint2);
  if (szA > szB) szB = szA;
  unsigned short* xw = (unsigned short*)base;
  char* regB = base + ((szA + 255) & ~(size_t)255);
  unsigned short* h  = (unsigned short*)regB;
  uint2* ebuf        = (uint2*)regB;
  int* row_ptr = (int*)(regB + ((szB + 255) & ~(size_t)255));
  int* csr     = row_ptr + N + 1;
  int* counts  = csr + E;
  unsigned short* hw = xw;       // reuse after agg1_k consumed xw
  float* out = (float*)d_out;

  int rowsGrid = (N * 64 + 255) / 256;
  int gemmGrid = (N + 63) / 64;            // 4 waves x 16 rows per block
  int NBLK  = (E + CHUNK - 1) / CHUNK;
  int NBUCK = (N + 511) >> BSH;
  int M = NBUCK * NBLK;
  int* psum = counts + M + 1;
  unsigned short* w1s = (unsigned short*)(psum + 64);
  unsigned short* w2s = w1s + 8192;
  int scanBlocks = (M + 2047) / 2048;

  wcvt_k<<<1, 256, 0, stream>>>(W1, W2, w1s, w2s);
  gemm1_k<<<gemmGrid, 256, 0, stream>>>(x, W1, w1s, xw, N);

  // CSR build: bucket counts -> hierarchical scan -> partition -> local build
  pcount_k<<<NBLK, 256, 0, stream>>>(ei, counts, E, NBLK, NBUCK);
  scanA_k<<<scanBlocks, 256, 0, stream>>>(counts, psum, M);
  scanB_k<<<1, 256, 0, stream>>>(psum, scanBlocks);
  scanC_k<<<scanBlocks, 256, 0, stream>>>(counts, psum, M, E);
  partition_k<<<NBLK, 256, 0, stream>>>(counts, ei, ebuf, E, NBLK, NBUCK);
  build_k<<<NBUCK, 256, 0, stream>>>(ebuf, counts, row_ptr, csr, N, E, NBLK, NBUCK);

  agg1_k<<<rowsGrid, 256, 0, stream>>>(xw, row_ptr, csr, b1, h, N);
  gemm2_k<<<gemmGrid, 256, 0, stream>>>(h, W2, w2s, hw, N);
  agg2_ls_k<<<rowsGrid, 256, 0, stream>>>(hw, row_ptr, csr, b2, out, N);
}

// Round 9
// 264.701 us; speedup vs baseline: 3.7952x; 1.1432x over previous
//
#include <hip/hip_runtime.h>
#include <cstdint>
#include <cstddef>

#define F_IN  128
#define F_HID 64
#define F_OUT 40

#define BSH   9     // bucket = dst >> 9 (512 nodes/bucket)
#define NBMAX 256   // supports N <= 131072
#define CHUNK 4096  // edges per partition block

typedef __attribute__((ext_vector_type(8))) short short8;   // 8 bf16 = 4 VGPR
typedef __attribute__((ext_vector_type(4))) float f32x4;    // MFMA C/D

// bf16 <-> f32 helpers (RNE on pack; values are finite)
__device__ __forceinline__ unsigned short f2bf(float f) {
  unsigned u = __float_as_uint(f);
  u += 0x7fffu + ((u >> 16) & 1u);
  return (unsigned short)(u >> 16);
}
__device__ __forceinline__ float bf2f(unsigned short b) {
  return __uint_as_float((unsigned)b << 16);
}
__device__ __forceinline__ float bflo(unsigned u) { return __uint_as_float(u << 16); }
__device__ __forceinline__ float bfhi(unsigned u) { return __uint_as_float(u & 0xffff0000u); }
__device__ __forceinline__ unsigned packbf(float lo, float hi) {
  return (unsigned)f2bf(lo) | ((unsigned)f2bf(hi) << 16);
}

// ---------------------------------------------------------------------------
// Pre-swizzle W1/W2 into MFMA B-fragment lane order (bf16), one tiny block.
// B-frag (16x16x32): lane holds B^T[n=lane&15][k=(lane>>4)*8+j], j=0..7.
// ---------------------------------------------------------------------------
__global__ __launch_bounds__(256) void wcvt_k(const float* __restrict__ W1,
                                              const float* __restrict__ W2,
                                              unsigned short* __restrict__ w1s,
                                              unsigned short* __restrict__ w2s) {
  int t = threadIdx.x;
  for (int i = t; i < 8192; i += 256) {
    int f = i >> 9, r = i & 511;
    int lane = r >> 3, j = r & 7;
    int ct = f >> 2, ks = f & 3;
    int n = ct * 16 + (lane & 15);
    int k = ks * 32 + (lane >> 4) * 8 + j;
    w1s[i] = f2bf(W1[k * F_HID + n]);
  }
  for (int i = t; i < 3072; i += 256) {
    int f = i >> 9, r = i & 511;
    int lane = r >> 3, j = r & 7;
    int ct = f >> 1, ks = f & 1;
    int n = ct * 16 + (lane & 15);
    int k = ks * 32 + (lane >> 4) * 8 + j;
    w2s[i] = (n < F_OUT) ? f2bf(W2[k * F_OUT + n]) : (unsigned short)0;
  }
}

// ---------------------------------------------------------------------------
// FRONT (fused): blocks [0,NBLK) run pcount (per-chunk bucket counts, LDS
// only — starts the CSR critical path immediately); blocks [NBLK,+gemmBlks)
// run MFMA GEMM1 on the CUs pcount can't fill (hidden behind CSR build).
// GEMM1: xw[N,64](bf16) = x[N,128](f32) @ W1; wave = 16 rows, no LDS;
// A-frags from global f32 (coalesced 32B/lane) + inline cvt; B-frags from
// pre-swizzled L2-hot w1s. 16 x mfma_f32_16x16x32_bf16 per wave.
// ---------------------------------------------------------------------------
__global__ __launch_bounds__(256) void front_k(const float* __restrict__ x,
                                               const float* __restrict__ W1,
                                               const unsigned short* __restrict__ w1s,
                                               unsigned short* __restrict__ xw, int N,
                                               const int* __restrict__ ei,
                                               int* __restrict__ counts,
                                               int E, int NBLK, int NBUCK) {
  __shared__ int lh[NBMAX];
  if ((int)blockIdx.x < NBLK) {
    // ---- pcount ----
    int t = threadIdx.x, blk = blockIdx.x;
    lh[t] = 0;
    __syncthreads();
    int e0 = blk * CHUNK;
    int n = min(CHUNK, E - e0);
    for (int i = t; i < n; i += 256)
      atomicAdd(&lh[((unsigned)ei[E + e0 + i]) >> BSH], 1);
    __syncthreads();
    if (t < NBUCK) counts[t * NBLK + blk] = lh[t];
    return;
  }
  // ---- gemm1 ----
  int gblk = blockIdx.x - NBLK;
  int lane = threadIdx.x & 63;
  int wid  = gblk * 4 + (threadIdx.x >> 6);
  int row0 = wid * 16;
  if (row0 >= N) return;
  int m = lane & 15, q = lane >> 4;

  if (row0 + 16 <= N) {
    short8 b[16];
#pragma unroll
    for (int f = 0; f < 16; ++f)
      b[f] = *(const short8*)(w1s + f * 512 + lane * 8);

    short8 a[4];
#pragma unroll
    for (int ks = 0; ks < 4; ++ks) {
      const float* xp = x + (size_t)(row0 + m) * F_IN + ks * 32 + q * 8;
      float4 v0 = *(const float4*)xp;
      float4 v1 = *(const float4*)(xp + 4);
      short8 t;
      t[0] = (short)f2bf(v0.x); t[1] = (short)f2bf(v0.y);
      t[2] = (short)f2bf(v0.z); t[3] = (short)f2bf(v0.w);
      t[4] = (short)f2bf(v1.x); t[5] = (short)f2bf(v1.y);
      t[6] = (short)f2bf(v1.z); t[7] = (short)f2bf(v1.w);
      a[ks] = t;
    }

    f32x4 z = {0.f, 0.f, 0.f, 0.f};
    f32x4 acc[4] = {z, z, z, z};
#pragma unroll
    for (int ct = 0; ct < 4; ++ct)
#pragma unroll
      for (int ks = 0; ks < 4; ++ks)
        acc[ct] = __builtin_amdgcn_mfma_f32_16x16x32_bf16(a[ks], b[ct * 4 + ks],
                                                          acc[ct], 0, 0, 0);
#pragma unroll
    for (int ct = 0; ct < 4; ++ct)
#pragma unroll
      for (int r = 0; r < 4; ++r) {
        int row = row0 + q * 4 + r;                 // D: col=lane&15, row=q*4+reg
        xw[(size_t)row * F_HID + ct * 16 + m] = f2bf(acc[ct][r]);
      }
  } else {
    for (int r = 0; r < 16 && row0 + r < N; ++r) { // tail: col = lane
      const float* xr = x + (size_t)(row0 + r) * F_IN;
      float s = 0.f;
      for (int k = 0; k < F_IN; ++k) s = fmaf(xr[k], W1[k * F_HID + lane], s);
      xw[(size_t)(row0 + r) * F_HID + lane] = f2bf(s);
    }
  }
}

// ---------------------------------------------------------------------------
// Hierarchical exclusive scan of counts[0..M-1], sentinel counts[M]=E.
// ---------------------------------------------------------------------------
__global__ __launch_bounds__(256) void scanA_k(const int* __restrict__ a,
                                               int* __restrict__ psum, int M) {
  int t = threadIdx.x;
  int base = blockIdx.x * 2048 + t * 8;
  int s = 0;
#pragma unroll
  for (int j = 0; j < 8; ++j) if (base + j < M) s += a[base + j];
#pragma unroll
  for (int off = 32; off; off >>= 1) s += __shfl_xor(s, off, 64);
  __shared__ int sm[4];
  if ((t & 63) == 0) sm[t >> 6] = s;
  __syncthreads();
  if (t == 0) psum[blockIdx.x] = sm[0] + sm[1] + sm[2] + sm[3];
}

__global__ __launch_bounds__(256) void scanB_k(int* __restrict__ psum, int nb) {
  __shared__ int sm[256];
  int t = threadIdx.x;
  int v = (t < nb) ? psum[t] : 0;
  sm[t] = v;
  __syncthreads();
  for (int off = 1; off < 256; off <<= 1) {
    int add = (t >= off) ? sm[t - off] : 0;
    __syncthreads();
    sm[t] += add;
    __syncthreads();
  }
  if (t < nb) psum[t] = sm[t] - v;     // exclusive
}

__global__ __launch_bounds__(256) void scanC_k(int* __restrict__ a,
                                               const int* __restrict__ psum,
                                               int M, int E) {
  __shared__ int sm[256];
  int t = threadIdx.x;
  int base = blockIdx.x * 2048 + t * 8;
  int v[8];
  int s = 0;
#pragma unroll
  for (int j = 0; j < 8; ++j) {
    v[j] = (base + j < M) ? a[base + j] : 0;
    s += v[j];
  }
  sm[t] = s;
  __syncthreads();
  for (int off = 1; off < 256; off <<= 1) {
    int add = (t >= off) ? sm[t - off] : 0;
    __syncthreads();
    sm[t] += add;
    __syncthreads();
  }
  int run = psum[blockIdx.x] + sm[t] - s;
#pragma unroll
  for (int j = 0; j < 8; ++j) {
    if (base + j < M) a[base + j] = run;
    run += v[j];
  }
  if (blockIdx.x == 0 && t == 0) a[M] = E;   // sentinel
}

// ---------------------------------------------------------------------------
// Multisplit P2: stable partition of (src,dst) into bucket-major ebuf.
// ---------------------------------------------------------------------------
__global__ __launch_bounds__(256) void partition_k(const int* __restrict__ bases,
                                                   const int* __restrict__ ei,
                                                   uint2* __restrict__ ebuf,
                                                   int E, int NBLK, int NBUCK) {
  __shared__ uint2 slots[CHUNK];          // 32 KB
  __shared__ int scn[NBMAX], lcur[NBMAX], gadj[NBMAX];
  int t = threadIdx.x, blk = blockIdx.x;
  int e0 = blk * CHUNK;
  int n = min(CHUNK, E - e0);

  int i0 = t * NBLK + blk;
  int cnt = 0, base0 = 0;
  if (t < NBUCK) {
    base0 = bases[i0];
    cnt = bases[i0 + 1] - base0;
  }
  scn[t] = cnt;
  __syncthreads();
  for (int off = 1; off < 256; off <<= 1) {
    int add = (t >= off) ? scn[t - off] : 0;
    __syncthreads();
    scn[t] += add;
    __syncthreads();
  }
  int excl = scn[t] - cnt;
  if (t < NBUCK) { lcur[t] = excl; gadj[t] = base0 - excl; }
  __syncthreads();

  for (int i = t; i < n; i += 256) {
    int s = ei[e0 + i], d = ei[E + e0 + i];
    int pos = atomicAdd(&lcur[((unsigned)d) >> BSH], 1);
    slots[pos] = make_uint2((unsigned)s, (unsigned)d);
  }
  __syncthreads();
  for (int i = t; i < n; i += 256) {
    uint2 sd = slots[i];
    ebuf[gadj[sd.y >> BSH] + i] = sd;
  }
}

// ---------------------------------------------------------------------------
// Bucket-local CSR build: LDS histogram + scan -> row_ptr; LDS cursor fill.
// ---------------------------------------------------------------------------
__global__ __launch_bounds__(256) void build_k(const uint2* __restrict__ ebuf,
                                               const int* __restrict__ bases,
                                               int* __restrict__ row_ptr,
                                               int* __restrict__ csr,
                                               int N, int E, int NBLK, int NBUCK) {
  __shared__ int hist[512];
  __shared__ int psc[256];
  int t = threadIdx.x, b = blockIdx.x;
  int nodeBase = b << BSH;
  int S = bases[b * NBLK];
  int T = bases[(b + 1) * NBLK];

  hist[t] = 0; hist[t + 256] = 0;
  __syncthreads();
  for (int i = S + t; i < T; i += 256)
    atomicAdd(&hist[ebuf[i].y & 511u], 1);
  __syncthreads();

  int v0 = hist[2 * t], v1 = hist[2 * t + 1];
  int pair = v0 + v1;
  psc[t] = pair;
  __syncthreads();
  for (int off = 1; off < 256; off <<= 1) {
    int add = (t >= off) ? psc[t - off] : 0;
    __syncthreads();
    psc[t] += add;
    __syncthreads();
  }
  int ep = psc[t] - pair;
  int e0 = ep, e1 = ep + v0;

  int node0 = nodeBase + 2 * t;
  if (node0 < N) row_ptr[node0] = S + e0;
  if (node0 + 1 < N) row_ptr[node0 + 1] = S + e1;
  if (b == 0 && t == 0) row_ptr[N] = E;

  hist[2 * t] = e0; hist[2 * t + 1] = e1;   // reuse as cursors
  __syncthreads();
  for (int i = S + t; i < T; i += 256) {
    uint2 sd = ebuf[i];
    int pos = atomicAdd(&hist[sd.y & 511u], 1);
    csr[S + pos] = (int)sd.x;
  }
}

// ---------------------------------------------------------------------------
// Aggregation layer 1 + bias1 + ReLU. 8 edges per gather instruction
// (slot=lane>>3 edge, part=lane&7 16-B row segment), 2-deep unroll so two
// gathers are in flight per wave; butterfly over slot bits reduces.
// ---------------------------------------------------------------------------
__global__ __launch_bounds__(256) void agg1_k(const unsigned short* __restrict__ xw,
                                              const int* __restrict__ row_ptr,
                                              const int* __restrict__ csr,
                                              const float* __restrict__ b1,
                                              unsigned short* __restrict__ h, int N) {
  int row = (blockIdx.x * 256 + threadIdx.x) >> 6;
  int lane = threadIdx.x & 63;
  if (row >= N) return;
  int slot = lane >> 3, part = lane & 7;
  int start = row_ptr[row], end = row_ptr[row + 1];

  float acc[8], bcc[8];
#pragma unroll
  for (int j = 0; j < 8; ++j) { acc[j] = 0.f; bcc[j] = 0.f; }

  for (int base = start; base < end; base += 16) {
    int i0 = base + slot, i1 = base + 8 + slot;
    if (i0 < end) {
      int s = csr[i0];
      uint4 v = *(const uint4*)(xw + ((size_t)s << 6) + (part << 3));
      acc[0] += bflo(v.x); acc[1] += bfhi(v.x);
      acc[2] += bflo(v.y); acc[3] += bfhi(v.y);
      acc[4] += bflo(v.z); acc[5] += bfhi(v.z);
      acc[6] += bflo(v.w); acc[7] += bfhi(v.w);
    }
    if (i1 < end) {
      int s = csr[i1];
      uint4 v = *(const uint4*)(xw + ((size_t)s << 6) + (part << 3));
      bcc[0] += bflo(v.x); bcc[1] += bfhi(v.x);
      bcc[2] += bflo(v.y); bcc[3] += bfhi(v.y);
      bcc[4] += bflo(v.z); bcc[5] += bfhi(v.z);
      bcc[6] += bflo(v.w); bcc[7] += bfhi(v.w);
    }
  }
#pragma unroll
  for (int j = 0; j < 8; ++j) acc[j] += bcc[j];
#pragma unroll
  for (int off = 8; off < 64; off <<= 1) {
#pragma unroll
    for (int j = 0; j < 8; ++j) acc[j] += __shfl_xor(acc[j], off, 64);
  }
  if (slot == 0) {
    int c0 = part << 3;
    float4 bA = *(const float4*)(b1 + c0);
    float4 bB = *(const float4*)(b1 + c0 + 4);
    float r0 = fmaxf(acc[0] + bA.x, 0.f), r1 = fmaxf(acc[1] + bA.y, 0.f);
    float r2 = fmaxf(acc[2] + bA.z, 0.f), r3 = fmaxf(acc[3] + bA.w, 0.f);
    float r4 = fmaxf(acc[4] + bB.x, 0.f), r5 = fmaxf(acc[5] + bB.y, 0.f);
    float r6 = fmaxf(acc[6] + bB.z, 0.f), r7 = fmaxf(acc[7] + bB.w, 0.f);
    uint4 o = make_uint4(packbf(r0, r1), packbf(r2, r3), packbf(r4, r5), packbf(r6, r7));
    *(uint4*)(h + ((size_t)row << 6) + c0) = o;
  }
}

// ---------------------------------------------------------------------------
// GEMM2 (MFMA): hw[N,64](bf16) = h[N,64](bf16) @ W2[64,40]; cols 40..63 = 0.
// ---------------------------------------------------------------------------
__global__ __launch_bounds__(256) void gemm2_k(const unsigned short* __restrict__ h,
                                               const float* __restrict__ W2,
                                               const unsigned short* __restrict__ w2s,
                                               unsigned short* __restrict__ hw, int N) {
  int lane = threadIdx.x & 63;
  int wid  = (blockIdx.x * 256 + threadIdx.x) >> 6;
  int row0 = wid * 16;
  if (row0 >= N) return;
  int m = lane & 15, q = lane >> 4;

  if (row0 + 16 <= N) {
    short8 b[6];
#pragma unroll
    for (int f = 0; f < 6; ++f)
      b[f] = *(const short8*)(w2s + f * 512 + lane * 8);

    short8 a[2];
#pragma unroll
    for (int ks = 0; ks < 2; ++ks)
      a[ks] = *(const short8*)(h + (size_t)(row0 + m) * F_HID + ks * 32 + q * 8);

    f32x4 z = {0.f, 0.f, 0.f, 0.f};
    f32x4 acc[3] = {z, z, z};
#pragma unroll
    for (int ct = 0; ct < 3; ++ct)
#pragma unroll
      for (int ks = 0; ks < 2; ++ks)
        acc[ct] = __builtin_amdgcn_mfma_f32_16x16x32_bf16(a[ks], b[ct * 2 + ks],
                                                          acc[ct], 0, 0, 0);
#pragma unroll
    for (int ct = 0; ct < 3; ++ct)
#pragma unroll
      for (int r = 0; r < 4; ++r) {
        int row = row0 + q * 4 + r;
        int c = ct * 16 + m;
        hw[(size_t)row * F_HID + c] = (c < F_OUT) ? f2bf(acc[ct][r]) : (unsigned short)0;
      }
#pragma unroll
    for (int r = 0; r < 4; ++r) {
      int row = row0 + q * 4 + r;
      hw[(size_t)row * F_HID + 48 + m] = 0;
    }
  } else {
    for (int r = 0; r < 16 && row0 + r < N; ++r) {   // tail: col = lane
      const unsigned short* hr = h + (size_t)(row0 + r) * F_HID;
      float s = 0.f;
      if (lane < F_OUT)
        for (int k = 0; k < F_HID; ++k) s = fmaf(bf2f(hr[k]), W2[k * F_OUT + lane], s);
      hw[(size_t)(row0 + r) * F_HID + lane] =
          (lane < F_OUT) ? f2bf(s) : (unsigned short)0;
    }
  }
}

// ---------------------------------------------------------------------------
// Aggregation layer 2 (8-edges-per-gather, 2-deep unroll) + bias2 +
// log_softmax. parts 0..4 hold cols 0..39.
// ---------------------------------------------------------------------------
__global__ __launch_bounds__(256) void agg2_ls_k(const unsigned short* __restrict__ hw,
                                                 const int* __restrict__ row_ptr,
                                                 const int* __restrict__ csr,
                                                 const float* __restrict__ b2,
                                                 float* __restrict__ out, int N) {
  int row = (blockIdx.x * 256 + threadIdx.x) >> 6;
  int lane = threadIdx.x & 63;
  if (row >= N) return;
  int slot = lane >> 3, part = lane & 7;
  int start = row_ptr[row], end = row_ptr[row + 1];

  float acc[8], bcc[8];
#pragma unroll
  for (int j = 0; j < 8; ++j) { acc[j] = 0.f; bcc[j] = 0.f; }

  for (int base = start; base < end; base += 16) {
    int i0 = base + slot, i1 = base + 8 + slot;
    if (i0 < end) {
      int s = csr[i0];
      uint4 v = *(const uint4*)(hw + ((size_t)s << 6) + (part << 3));
      acc[0] += bflo(v.x); acc[1] += bfhi(v.x);
      acc[2] += bflo(v.y); acc[3] += bfhi(v.y);
      acc[4] += bflo(v.z); acc[5] += bfhi(v.z);
      acc[6] += bflo(v.w); acc[7] += bfhi(v.w);
    }
    if (i1 < end) {
      int s = csr[i1];
      uint4 v = *(const uint4*)(hw + ((size_t)s << 6) + (part << 3));
      bcc[0] += bflo(v.x); bcc[1] += bfhi(v.x);
      bcc[2] += bflo(v.y); bcc[3] += bfhi(v.y);
      bcc[4] += bflo(v.z); bcc[5] += bfhi(v.z);
      bcc[6] += bflo(v.w); bcc[7] += bfhi(v.w);
    }
  }
#pragma unroll
  for (int j = 0; j < 8; ++j) acc[j] += bcc[j];
#pragma unroll
  for (int off = 8; off < 64; off <<= 1) {
#pragma unroll
    for (int j = 0; j < 8; ++j) acc[j] += __shfl_xor(acc[j], off, 64);
  }

  float vj[8];
  float m = -3.4e38f;
  if (part < 5) {
    int c0 = part << 3;
    float4 bA = *(const float4*)(b2 + c0);
    float4 bB = *(const float4*)(b2 + c0 + 4);
    vj[0] = acc[0] + bA.x; vj[1] = acc[1] + bA.y;
    vj[2] = acc[2] + bA.z; vj[3] = acc[3] + bA.w;
    vj[4] = acc[4] + bB.x; vj[5] = acc[5] + bB.y;
    vj[6] = acc[6] + bB.z; vj[7] = acc[7] + bB.w;
#pragma unroll
    for (int j = 0; j < 8; ++j) m = fmaxf(m, vj[j]);
  }
#pragma unroll
  for (int off = 1; off < 8; off <<= 1) m = fmaxf(m, __shfl_xor(m, off, 64));
  float ex = 0.f;
  if (part < 5) {
#pragma unroll
    for (int j = 0; j < 8; ++j) ex += __expf(vj[j] - m);
  }
#pragma unroll
  for (int off = 1; off < 8; off <<= 1) ex += __shfl_xor(ex, off, 64);
  float lse = __logf(ex) + m;

  if (slot == 0 && part < 5) {
    int c0 = part << 3;
    float* op = out + (size_t)row * F_OUT + c0;
    *(float4*)op = make_float4(vj[0] - lse, vj[1] - lse, vj[2] - lse, vj[3] - lse);
    *(float4*)(op + 4) = make_float4(vj[4] - lse, vj[5] - lse, vj[6] - lse, vj[7] - lse);
  }
}

// ---------------------------------------------------------------------------
// ws layout (≈45 MB):
//   regA : xw[N,64] bf16 — reused as hw by gemm2 (xw dead then)
//   regB : ebuf[E] uint2 — reused as h[N,64] bf16 (ebuf dead then)
//   row_ptr : N+1 | csr : E | counts : M+1 | psum : 64 | w1s : 8192 | w2s : 3072
// ---------------------------------------------------------------------------
extern "C" void kernel_launch(void* const* d_in, const int* in_sizes, int n_in,
                              void* d_out, int out_size, void* d_ws, size_t ws_size,
                              hipStream_t stream) {
  const float* x  = (const float*)d_in[0];
  const int*   ei = (const int*)d_in[1];
  const float* W1 = (const float*)d_in[2];
  const float* b1 = (const float*)d_in[3];
  const float* W2 = (const float*)d_in[4];
  const float* b2 = (const float*)d_in[5];

  int N = in_sizes[0] / F_IN;
  int E = in_sizes[1] / 2;

  char* base = (char*)d_ws;
  size_t szA = (size_t)N * F_HID * sizeof(unsigned short);
  size_t szB = (size_t)E * sizeof(uint2);
  if (szA > szB) szB = szA;
  unsigned short* xw = (unsigned short*)base;
  char* regB = base + ((szA + 255) & ~(size_t)255);
  unsigned short* h  = (unsigned short*)regB;
  uint2* ebuf        = (uint2*)regB;
  int* row_ptr = (int*)(regB + ((szB + 255) & ~(size_t)255));
  int* csr     = row_ptr + N + 1;
  int* counts  = csr + E;
  unsigned short* hw = xw;       // reuse after agg1_k consumed xw
  float* out = (float*)d_out;

  int rowsGrid = (N * 64 + 255) / 256;
  int gemmGrid = (N + 63) / 64;            // 4 waves x 16 rows per block
  int NBLK  = (E + CHUNK - 1) / CHUNK;
  int NBUCK = (N + 511) >> BSH;
  int M = NBUCK * NBLK;
  int* psum = counts + M + 1;
  unsigned short* w1s = (unsigned short*)(psum + 64);
  unsigned short* w2s = w1s + 8192;
  int scanBlocks = (M + 2047) / 2048;

  wcvt_k<<<1, 256, 0, stream>>>(W1, W2, w1s, w2s);

  // fused: pcount (blocks 0..NBLK-1) + gemm1 (remaining blocks)
  front_k<<<NBLK + gemmGrid, 256, 0, stream>>>(x, W1, w1s, xw, N,
                                               ei, counts, E, NBLK, NBUCK);

  scanA_k<<<scanBlocks, 256, 0, stream>>>(counts, psum, M);
  scanB_k<<<1, 256, 0, stream>>>(psum, scanBlocks);
  scanC_k<<<scanBlocks, 256, 0, stream>>>(counts, psum, M, E);
  partition_k<<<NBLK, 256, 0, stream>>>(counts, ei, ebuf, E, NBLK, NBUCK);
  build_k<<<NBUCK, 256, 0, stream>>>(ebuf, counts, row_ptr, csr, N, E, NBLK, NBUCK);

  agg1_k<<<rowsGrid, 256, 0, stream>>>(xw, row_ptr, csr, b1, h, N);
  gemm2_k<<<gemmGrid, 256, 0, stream>>>(h, W2, w2s, hw, N);
  agg2_ls_k<<<rowsGrid, 256, 0, stream>>>(hw, row_ptr, csr, b2, out, N);
}

// Round 10
// 236.319 us; speedup vs baseline: 4.2510x; 1.1201x over previous
//
#include <hip/hip_runtime.h>
#include <cstdint>
#include <cstddef>

#define F_IN  128
#define F_HID 64
#define F_OUT 40

#define BSH   9     // bucket = dst >> 9 (512 nodes/bucket)
#define NBMAX 256   // supports N <= 131072
#define CHUNK 4096  // edges per partition block

typedef __attribute__((ext_vector_type(8))) short short8;   // 8 bf16 = 4 VGPR
typedef __attribute__((ext_vector_type(4))) float f32x4;    // MFMA C/D

// bf16 <-> f32 helpers (RNE on pack; values are finite)
__device__ __forceinline__ unsigned short f2bf(float f) {
  unsigned u = __float_as_uint(f);
  u += 0x7fffu + ((u >> 16) & 1u);
  return (unsigned short)(u >> 16);
}
__device__ __forceinline__ float bf2f(unsigned short b) {
  return __uint_as_float((unsigned)b << 16);
}
__device__ __forceinline__ float bflo(unsigned u) { return __uint_as_float(u << 16); }
__device__ __forceinline__ float bfhi(unsigned u) { return __uint_as_float(u & 0xffff0000u); }
__device__ __forceinline__ unsigned packbf(float lo, float hi) {
  return (unsigned)f2bf(lo) | ((unsigned)f2bf(hi) << 16);
}

// ---------------------------------------------------------------------------
// Pre-swizzle W1/W2 into MFMA B-fragment lane order (bf16), one tiny block.
// B-frag (16x16x32): lane holds B^T[n=lane&15][k=(lane>>4)*8+j], j=0..7.
// ---------------------------------------------------------------------------
__global__ __launch_bounds__(256) void wcvt_k(const float* __restrict__ W1,
                                              const float* __restrict__ W2,
                                              unsigned short* __restrict__ w1s,
                                              unsigned short* __restrict__ w2s) {
  int t = threadIdx.x;
  for (int i = t; i < 8192; i += 256) {
    int f = i >> 9, r = i & 511;
    int lane = r >> 3, j = r & 7;
    int ct = f >> 2, ks = f & 3;
    int n = ct * 16 + (lane & 15);
    int k = ks * 32 + (lane >> 4) * 8 + j;
    w1s[i] = f2bf(W1[k * F_HID + n]);
  }
  for (int i = t; i < 3072; i += 256) {
    int f = i >> 9, r = i & 511;
    int lane = r >> 3, j = r & 7;
    int ct = f >> 1, ks = f & 1;
    int n = ct * 16 + (lane & 15);
    int k = ks * 32 + (lane >> 4) * 8 + j;
    w2s[i] = (n < F_OUT) ? f2bf(W2[k * F_OUT + n]) : (unsigned short)0;
  }
}

// ---------------------------------------------------------------------------
// FRONT (fused): blocks [0,NBLK) run pcount; blocks [NBLK,+gemmBlks) run
// MFMA GEMM1 on CUs pcount can't fill.
// ---------------------------------------------------------------------------
__global__ __launch_bounds__(256) void front_k(const float* __restrict__ x,
                                               const float* __restrict__ W1,
                                               const unsigned short* __restrict__ w1s,
                                               unsigned short* __restrict__ xw, int N,
                                               const int* __restrict__ ei,
                                               int* __restrict__ counts,
                                               int E, int NBLK, int NBUCK) {
  __shared__ int lh[NBMAX];
  if ((int)blockIdx.x < NBLK) {
    // ---- pcount ----
    int t = threadIdx.x, blk = blockIdx.x;
    lh[t] = 0;
    __syncthreads();
    int e0 = blk * CHUNK;
    int n = min(CHUNK, E - e0);
    for (int i = t; i < n; i += 256)
      atomicAdd(&lh[((unsigned)ei[E + e0 + i]) >> BSH], 1);
    __syncthreads();
    if (t < NBUCK) counts[t * NBLK + blk] = lh[t];
    return;
  }
  // ---- gemm1 ----
  int gblk = blockIdx.x - NBLK;
  int lane = threadIdx.x & 63;
  int wid  = gblk * 4 + (threadIdx.x >> 6);
  int row0 = wid * 16;
  if (row0 >= N) return;
  int m = lane & 15, q = lane >> 4;

  if (row0 + 16 <= N) {
    short8 b[16];
#pragma unroll
    for (int f = 0; f < 16; ++f)
      b[f] = *(const short8*)(w1s + f * 512 + lane * 8);

    short8 a[4];
#pragma unroll
    for (int ks = 0; ks < 4; ++ks) {
      const float* xp = x + (size_t)(row0 + m) * F_IN + ks * 32 + q * 8;
      float4 v0 = *(const float4*)xp;
      float4 v1 = *(const float4*)(xp + 4);
      short8 t;
      t[0] = (short)f2bf(v0.x); t[1] = (short)f2bf(v0.y);
      t[2] = (short)f2bf(v0.z); t[3] = (short)f2bf(v0.w);
      t[4] = (short)f2bf(v1.x); t[5] = (short)f2bf(v1.y);
      t[6] = (short)f2bf(v1.z); t[7] = (short)f2bf(v1.w);
      a[ks] = t;
    }

    f32x4 z = {0.f, 0.f, 0.f, 0.f};
    f32x4 acc[4] = {z, z, z, z};
#pragma unroll
    for (int ct = 0; ct < 4; ++ct)
#pragma unroll
      for (int ks = 0; ks < 4; ++ks)
        acc[ct] = __builtin_amdgcn_mfma_f32_16x16x32_bf16(a[ks], b[ct * 4 + ks],
                                                          acc[ct], 0, 0, 0);
#pragma unroll
    for (int ct = 0; ct < 4; ++ct)
#pragma unroll
      for (int r = 0; r < 4; ++r) {
        int row = row0 + q * 4 + r;                 // D: col=lane&15, row=q*4+reg
        xw[(size_t)row * F_HID + ct * 16 + m] = f2bf(acc[ct][r]);
      }
  } else {
    for (int r = 0; r < 16 && row0 + r < N; ++r) { // tail: col = lane
      const float* xr = x + (size_t)(row0 + r) * F_IN;
      float s = 0.f;
      for (int k = 0; k < F_IN; ++k) s = fmaf(xr[k], W1[k * F_HID + lane], s);
      xw[(size_t)(row0 + r) * F_HID + lane] = f2bf(s);
    }
  }
}

// ---------------------------------------------------------------------------
// Hierarchical exclusive scan of counts[0..M-1], sentinel counts[M]=E.
// ---------------------------------------------------------------------------
__global__ __launch_bounds__(256) void scanA_k(const int* __restrict__ a,
                                               int* __restrict__ psum, int M) {
  int t = threadIdx.x;
  int base = blockIdx.x * 2048 + t * 8;
  int s = 0;
#pragma unroll
  for (int j = 0; j < 8; ++j) if (base + j < M) s += a[base + j];
#pragma unroll
  for (int off = 32; off; off >>= 1) s += __shfl_xor(s, off, 64);
  __shared__ int sm[4];
  if ((t & 63) == 0) sm[t >> 6] = s;
  __syncthreads();
  if (t == 0) psum[blockIdx.x] = sm[0] + sm[1] + sm[2] + sm[3];
}

__global__ __launch_bounds__(256) void scanB_k(int* __restrict__ psum, int nb) {
  __shared__ int sm[256];
  int t = threadIdx.x;
  int v = (t < nb) ? psum[t] : 0;
  sm[t] = v;
  __syncthreads();
  for (int off = 1; off < 256; off <<= 1) {
    int add = (t >= off) ? sm[t - off] : 0;
    __syncthreads();
    sm[t] += add;
    __syncthreads();
  }
  if (t < nb) psum[t] = sm[t] - v;     // exclusive
}

__global__ __launch_bounds__(256) void scanC_k(int* __restrict__ a,
                                               const int* __restrict__ psum,
                                               int M, int E) {
  __shared__ int sm[256];
  int t = threadIdx.x;
  int base = blockIdx.x * 2048 + t * 8;
  int v[8];
  int s = 0;
#pragma unroll
  for (int j = 0; j < 8; ++j) {
    v[j] = (base + j < M) ? a[base + j] : 0;
    s += v[j];
  }
  sm[t] = s;
  __syncthreads();
  for (int off = 1; off < 256; off <<= 1) {
    int add = (t >= off) ? sm[t - off] : 0;
    __syncthreads();
    sm[t] += add;
    __syncthreads();
  }
  int run = psum[blockIdx.x] + sm[t] - s;
#pragma unroll
  for (int j = 0; j < 8; ++j) {
    if (base + j < M) a[base + j] = run;
    run += v[j];
  }
  if (blockIdx.x == 0 && t == 0) a[M] = E;   // sentinel
}

// ---------------------------------------------------------------------------
// Multisplit P2: stable partition of (src,dst) into bucket-major ebuf.
// ---------------------------------------------------------------------------
__global__ __launch_bounds__(256) void partition_k(const int* __restrict__ bases,
                                                   const int* __restrict__ ei,
                                                   uint2* __restrict__ ebuf,
                                                   int E, int NBLK, int NBUCK) {
  __shared__ uint2 slots[CHUNK];          // 32 KB
  __shared__ int scn[NBMAX], lcur[NBMAX], gadj[NBMAX];
  int t = threadIdx.x, blk = blockIdx.x;
  int e0 = blk * CHUNK;
  int n = min(CHUNK, E - e0);

  int i0 = t * NBLK + blk;
  int cnt = 0, base0 = 0;
  if (t < NBUCK) {
    base0 = bases[i0];
    cnt = bases[i0 + 1] - base0;
  }
  scn[t] = cnt;
  __syncthreads();
  for (int off = 1; off < 256; off <<= 1) {
    int add = (t >= off) ? scn[t - off] : 0;
    __syncthreads();
    scn[t] += add;
    __syncthreads();
  }
  int excl = scn[t] - cnt;
  if (t < NBUCK) { lcur[t] = excl; gadj[t] = base0 - excl; }
  __syncthreads();

  for (int i = t; i < n; i += 256) {
    int s = ei[e0 + i], d = ei[E + e0 + i];
    int pos = atomicAdd(&lcur[((unsigned)d) >> BSH], 1);
    slots[pos] = make_uint2((unsigned)s, (unsigned)d);
  }
  __syncthreads();
  for (int i = t; i < n; i += 256) {
    uint2 sd = slots[i];
    ebuf[gadj[sd.y >> BSH] + i] = sd;
  }
}

// ---------------------------------------------------------------------------
// Bucket-local CSR build: LDS histogram + scan -> row_ptr; LDS cursor fill.
// ---------------------------------------------------------------------------
__global__ __launch_bounds__(256) void build_k(const uint2* __restrict__ ebuf,
                                               const int* __restrict__ bases,
                                               int* __restrict__ row_ptr,
                                               int* __restrict__ csr,
                                               int N, int E, int NBLK, int NBUCK) {
  __shared__ int hist[512];
  __shared__ int psc[256];
  int t = threadIdx.x, b = blockIdx.x;
  int nodeBase = b << BSH;
  int S = bases[b * NBLK];
  int T = bases[(b + 1) * NBLK];

  hist[t] = 0; hist[t + 256] = 0;
  __syncthreads();
  for (int i = S + t; i < T; i += 256)
    atomicAdd(&hist[ebuf[i].y & 511u], 1);
  __syncthreads();

  int v0 = hist[2 * t], v1 = hist[2 * t + 1];
  int pair = v0 + v1;
  psc[t] = pair;
  __syncthreads();
  for (int off = 1; off < 256; off <<= 1) {
    int add = (t >= off) ? psc[t - off] : 0;
    __syncthreads();
    psc[t] += add;
    __syncthreads();
  }
  int ep = psc[t] - pair;
  int e0 = ep, e1 = ep + v0;

  int node0 = nodeBase + 2 * t;
  if (node0 < N) row_ptr[node0] = S + e0;
  if (node0 + 1 < N) row_ptr[node0 + 1] = S + e1;
  if (b == 0 && t == 0) row_ptr[N] = E;

  hist[2 * t] = e0; hist[2 * t + 1] = e1;   // reuse as cursors
  __syncthreads();
  for (int i = S + t; i < T; i += 256) {
    uint2 sd = ebuf[i];
    int pos = atomicAdd(&hist[sd.y & 511u], 1);
    csr[S + pos] = (int)sd.x;
  }
}

// ---------------------------------------------------------------------------
// Aggregation layer 1 + bias1 + ReLU. Wave = 8 rows; lane = (row=lane>>3,
// part=lane&7 owning 8 cols = 16 B). Each lane walks its own row's edges,
// accumulating lane-privately — NO cross-lane butterfly. Gathers still
// cover 8 full 128-B rows per dwordx4; stores coalesce to 1 KB per wave.
// ---------------------------------------------------------------------------
__global__ __launch_bounds__(256) void agg1_k(const unsigned short* __restrict__ xw,
                                              const int* __restrict__ row_ptr,
                                              const int* __restrict__ csr,
                                              const float* __restrict__ b1,
                                              unsigned short* __restrict__ h, int N) {
  int wid = (blockIdx.x * 256 + threadIdx.x) >> 6;
  int lane = threadIdx.x & 63;
  int rowBase = wid * 8;
  if (rowBase >= N) return;
  int row = rowBase + (lane >> 3);
  int part = lane & 7;
  bool live = row < N;

  int start = live ? row_ptr[row] : 0;
  int end   = live ? row_ptr[row + 1] : 0;

  float acc[8], bcc[8];
#pragma unroll
  for (int j = 0; j < 8; ++j) { acc[j] = 0.f; bcc[j] = 0.f; }

  int i = start;
  for (; i + 1 < end; i += 2) {
    int s0 = csr[i];
    int s1 = csr[i + 1];
    uint4 v0 = *(const uint4*)(xw + ((size_t)s0 << 6) + (part << 3));
    uint4 v1 = *(const uint4*)(xw + ((size_t)s1 << 6) + (part << 3));
    acc[0] += bflo(v0.x); acc[1] += bfhi(v0.x);
    acc[2] += bflo(v0.y); acc[3] += bfhi(v0.y);
    acc[4] += bflo(v0.z); acc[5] += bfhi(v0.z);
    acc[6] += bflo(v0.w); acc[7] += bfhi(v0.w);
    bcc[0] += bflo(v1.x); bcc[1] += bfhi(v1.x);
    bcc[2] += bflo(v1.y); bcc[3] += bfhi(v1.y);
    bcc[4] += bflo(v1.z); bcc[5] += bfhi(v1.z);
    bcc[6] += bflo(v1.w); bcc[7] += bfhi(v1.w);
  }
  if (i < end) {
    int s = csr[i];
    uint4 v = *(const uint4*)(xw + ((size_t)s << 6) + (part << 3));
    acc[0] += bflo(v.x); acc[1] += bfhi(v.x);
    acc[2] += bflo(v.y); acc[3] += bfhi(v.y);
    acc[4] += bflo(v.z); acc[5] += bfhi(v.z);
    acc[6] += bflo(v.w); acc[7] += bfhi(v.w);
  }

  if (live) {
    int c0 = part << 3;
    float4 bA = *(const float4*)(b1 + c0);
    float4 bB = *(const float4*)(b1 + c0 + 4);
    float r0 = fmaxf(acc[0] + bcc[0] + bA.x, 0.f);
    float r1 = fmaxf(acc[1] + bcc[1] + bA.y, 0.f);
    float r2 = fmaxf(acc[2] + bcc[2] + bA.z, 0.f);
    float r3 = fmaxf(acc[3] + bcc[3] + bA.w, 0.f);
    float r4 = fmaxf(acc[4] + bcc[4] + bB.x, 0.f);
    float r5 = fmaxf(acc[5] + bcc[5] + bB.y, 0.f);
    float r6 = fmaxf(acc[6] + bcc[6] + bB.z, 0.f);
    float r7 = fmaxf(acc[7] + bcc[7] + bB.w, 0.f);
    uint4 o = make_uint4(packbf(r0, r1), packbf(r2, r3), packbf(r4, r5), packbf(r6, r7));
    *(uint4*)(h + ((size_t)row << 6) + c0) = o;
  }
}

// ---------------------------------------------------------------------------
// GEMM2 (MFMA): hw[N,64](bf16) = h[N,64](bf16) @ W2[64,40]; cols 40..63 = 0.
// ---------------------------------------------------------------------------
__global__ __launch_bounds__(256) void gemm2_k(const unsigned short* __restrict__ h,
                                               const float* __restrict__ W2,
                                               const unsigned short* __restrict__ w2s,
                                               unsigned short* __restrict__ hw, int N) {
  int lane = threadIdx.x & 63;
  int wid  = (blockIdx.x * 256 + threadIdx.x) >> 6;
  int row0 = wid * 16;
  if (row0 >= N) return;
  int m = lane & 15, q = lane >> 4;

  if (row0 + 16 <= N) {
    short8 b[6];
#pragma unroll
    for (int f = 0; f < 6; ++f)
      b[f] = *(const short8*)(w2s + f * 512 + lane * 8);

    short8 a[2];
#pragma unroll
    for (int ks = 0; ks < 2; ++ks)
      a[ks] = *(const short8*)(h + (size_t)(row0 + m) * F_HID + ks * 32 + q * 8);

    f32x4 z = {0.f, 0.f, 0.f, 0.f};
    f32x4 acc[3] = {z, z, z};
#pragma unroll
    for (int ct = 0; ct < 3; ++ct)
#pragma unroll
      for (int ks = 0; ks < 2; ++ks)
        acc[ct] = __builtin_amdgcn_mfma_f32_16x16x32_bf16(a[ks], b[ct * 2 + ks],
                                                          acc[ct], 0, 0, 0);
#pragma unroll
    for (int ct = 0; ct < 3; ++ct)
#pragma unroll
      for (int r = 0; r < 4; ++r) {
        int row = row0 + q * 4 + r;
        int c = ct * 16 + m;
        hw[(size_t)row * F_HID + c] = (c < F_OUT) ? f2bf(acc[ct][r]) : (unsigned short)0;
      }
#pragma unroll
    for (int r = 0; r < 4; ++r) {
      int row = row0 + q * 4 + r;
      hw[(size_t)row * F_HID + 48 + m] = 0;
    }
  } else {
    for (int r = 0; r < 16 && row0 + r < N; ++r) {   // tail: col = lane
      const unsigned short* hr = h + (size_t)(row0 + r) * F_HID;
      float s = 0.f;
      if (lane < F_OUT)
        for (int k = 0; k < F_HID; ++k) s = fmaf(bf2f(hr[k]), W2[k * F_OUT + lane], s);
      hw[(size_t)(row0 + r) * F_HID + lane] =
          (lane < F_OUT) ? f2bf(s) : (unsigned short)0;
    }
  }
}

// ---------------------------------------------------------------------------
// Aggregation layer 2 + bias2 + log_softmax. Wave = 8 rows, lane-private
// accumulation; softmax reduces over the low-3 lane bits only (parts 0..4
// hold cols 0..39; hw cols 40..63 are zero).
// ---------------------------------------------------------------------------
__global__ __launch_bounds__(256) void agg2_ls_k(const unsigned short* __restrict__ hw,
                                                 const int* __restrict__ row_ptr,
                                                 const int* __restrict__ csr,
                                                 const float* __restrict__ b2,
                                                 float* __restrict__ out, int N) {
  int wid = (blockIdx.x * 256 + threadIdx.x) >> 6;
  int lane = threadIdx.x & 63;
  int rowBase = wid * 8;
  if (rowBase >= N) return;
  int row = rowBase + (lane >> 3);
  int part = lane & 7;
  bool live = row < N;

  int start = live ? row_ptr[row] : 0;
  int end   = live ? row_ptr[row + 1] : 0;

  float acc[8], bcc[8];
#pragma unroll
  for (int j = 0; j < 8; ++j) { acc[j] = 0.f; bcc[j] = 0.f; }

  int i = start;
  for (; i + 1 < end; i += 2) {
    int s0 = csr[i];
    int s1 = csr[i + 1];
    uint4 v0 = *(const uint4*)(hw + ((size_t)s0 << 6) + (part << 3));
    uint4 v1 = *(const uint4*)(hw + ((size_t)s1 << 6) + (part << 3));
    acc[0] += bflo(v0.x); acc[1] += bfhi(v0.x);
    acc[2] += bflo(v0.y); acc[3] += bfhi(v0.y);
    acc[4] += bflo(v0.z); acc[5] += bfhi(v0.z);
    acc[6] += bflo(v0.w); acc[7] += bfhi(v0.w);
    bcc[0] += bflo(v1.x); bcc[1] += bfhi(v1.x);
    bcc[2] += bflo(v1.y); bcc[3] += bfhi(v1.y);
    bcc[4] += bflo(v1.z); bcc[5] += bfhi(v1.z);
    bcc[6] += bflo(v1.w); bcc[7] += bfhi(v1.w);
  }
  if (i < end) {
    int s = csr[i];
    uint4 v = *(const uint4*)(hw + ((size_t)s << 6) + (part << 3));
    acc[0] += bflo(v.x); acc[1] += bfhi(v.x);
    acc[2] += bflo(v.y); acc[3] += bfhi(v.y);
    acc[4] += bflo(v.z); acc[5] += bfhi(v.z);
    acc[6] += bflo(v.w); acc[7] += bfhi(v.w);
  }

  bool valid = live && (part < 5);
  float vj[8];
  float m = -3.4e38f;
  if (valid) {
    int c0 = part << 3;
    float4 bA = *(const float4*)(b2 + c0);
    float4 bB = *(const float4*)(b2 + c0 + 4);
    vj[0] = acc[0] + bcc[0] + bA.x; vj[1] = acc[1] + bcc[1] + bA.y;
    vj[2] = acc[2] + bcc[2] + bA.z; vj[3] = acc[3] + bcc[3] + bA.w;
    vj[4] = acc[4] + bcc[4] + bB.x; vj[5] = acc[5] + bcc[5] + bB.y;
    vj[6] = acc[6] + bcc[6] + bB.z; vj[7] = acc[7] + bcc[7] + bB.w;
#pragma unroll
    for (int j = 0; j < 8; ++j) m = fmaxf(m, vj[j]);
  }
#pragma unroll
  for (int off = 1; off < 8; off <<= 1) m = fmaxf(m, __shfl_xor(m, off, 64));
  float ex = 0.f;
  if (valid) {
#pragma unroll
    for (int j = 0; j < 8; ++j) ex += __expf(vj[j] - m);
  }
#pragma unroll
  for (int off = 1; off < 8; off <<= 1) ex += __shfl_xor(ex, off, 64);
  float lse = __logf(ex) + m;

  if (valid) {
    int c0 = part << 3;
    float* op = out + (size_t)row * F_OUT + c0;
    *(float4*)op = make_float4(vj[0] - lse, vj[1] - lse, vj[2] - lse, vj[3] - lse);
    *(float4*)(op + 4) = make_float4(vj[4] - lse, vj[5] - lse, vj[6] - lse, vj[7] - lse);
  }
}

// ---------------------------------------------------------------------------
// ws layout (≈45 MB):
//   regA : xw[N,64] bf16 — reused as hw by gemm2 (xw dead then)
//   regB : ebuf[E] uint2 — reused as h[N,64] bf16 (ebuf dead then)
//   row_ptr : N+1 | csr : E | counts : M+1 | psum : 64 | w1s : 8192 | w2s : 3072
// ---------------------------------------------------------------------------
extern "C" void kernel_launch(void* const* d_in, const int* in_sizes, int n_in,
                              void* d_out, int out_size, void* d_ws, size_t ws_size,
                              hipStream_t stream) {
  const float* x  = (const float*)d_in[0];
  const int*   ei = (const int*)d_in[1];
  const float* W1 = (const float*)d_in[2];
  const float* b1 = (const float*)d_in[3];
  const float* W2 = (const float*)d_in[4];
  const float* b2 = (const float*)d_in[5];

  int N = in_sizes[0] / F_IN;
  int E = in_sizes[1] / 2;

  char* base = (char*)d_ws;
  size_t szA = (size_t)N * F_HID * sizeof(unsigned short);
  size_t szB = (size_t)E * sizeof(uint2);
  if (szA > szB) szB = szA;
  unsigned short* xw = (unsigned short*)base;
  char* regB = base + ((szA + 255) & ~(size_t)255);
  unsigned short* h  = (unsigned short*)regB;
  uint2* ebuf        = (uint2*)regB;
  int* row_ptr = (int*)(regB + ((szB + 255) & ~(size_t)255));
  int* csr     = row_ptr + N + 1;
  int* counts  = csr + E;
  unsigned short* hw = xw;       // reuse after agg1_k consumed xw
  float* out = (float*)d_out;

  int aggGrid  = (N * 8 + 255) / 256;      // 8 threads per row
  int gemmGrid = (N + 63) / 64;            // 4 waves x 16 rows per block
  int NBLK  = (E + CHUNK - 1) / CHUNK;
  int NBUCK = (N + 511) >> BSH;
  int M = NBUCK * NBLK;
  int* psum = counts + M + 1;
  unsigned short* w1s = (unsigned short*)(psum + 64);
  unsigned short* w2s = w1s + 8192;
  int scanBlocks = (M + 2047) / 2048;

  wcvt_k<<<1, 256, 0, stream>>>(W1, W2, w1s, w2s);

  // fused: pcount (blocks 0..NBLK-1) + gemm1 (remaining blocks)
  front_k<<<NBLK + gemmGrid, 256, 0, stream>>>(x, W1, w1s, xw, N,
                                               ei, counts, E, NBLK, NBUCK);

  scanA_k<<<scanBlocks, 256, 0, stream>>>(counts, psum, M);
  scanB_k<<<1, 256, 0, stream>>>(psum, scanBlocks);
  scanC_k<<<scanBlocks, 256, 0, stream>>>(counts, psum, M, E);
  partition_k<<<NBLK, 256, 0, stream>>>(counts, ei, ebuf, E, NBLK, NBUCK);
  build_k<<<NBUCK, 256, 0, stream>>>(ebuf, counts, row_ptr, csr, N, E, NBLK, NBUCK);

  agg1_k<<<aggGrid, 256, 0, stream>>>(xw, row_ptr, csr, b1, h, N);
  gemm2_k<<<gemmGrid, 256, 0, stream>>>(h, W2, w2s, hw, N);
  agg2_ls_k<<<aggGrid, 256, 0, stream>>>(hw, row_ptr, csr, b2, out, N);
}